// Round 14
// baseline (530.796 us; speedup 1.0000x reference)
//
#include <hip/hip_runtime.h>

// GATv2 3-layer + mean-pool + linear head, MI355X.
// R13: (1) CSR build reverted to R10's simple form — R12's 3-phase partition
//      measured ~19us SLOWER (pwrite barrier/ticket overhead + pairs
//      double-stream beat the redundancy it removed).
//      (2) gemm inner loop: x read as float4-per-4k (LDX=36 keeps 16B align)
//      — LDS issue per 4k drops 237->192 cyc, below the 384 VALU-cyc, so the
//      FMA pipe becomes the limiter.

#define NN 50000
#define NE 1000000
#define HID 64
#define DIN0 128
#define NG 256
#define NEG 0.2f

#define SCHUNK 1024
#define SNB ((NN + SCHUNK - 1) / SCHUNK)   // 49 blocks

// ---- CSR build ----
__global__ void k_zero_int(int* __restrict__ p, int n) {
    int i = blockIdx.x * 256 + threadIdx.x;
    if (i < n) p[i] = 0;
}

__global__ void k_hist(const int* __restrict__ edst, int* __restrict__ cnt) {
    int e = blockIdx.x * 256 + threadIdx.x;
    if (e < NE) atomicAdd(&cnt[edst[e]], 1);
}

__global__ __launch_bounds__(256) void k_scan_part(const int* __restrict__ cnt,
                                                   int* __restrict__ part) {
    __shared__ int ws[4];
    int b = blockIdx.x, t = threadIdx.x;
    int i0 = b * SCHUNK + t * 4;
    int s = 0;
#pragma unroll
    for (int j = 0; j < 4; j++) {
        int i = i0 + j;
        if (i < NN) s += cnt[i];
    }
#pragma unroll
    for (int o = 32; o; o >>= 1) s += __shfl_xor(s, o, 64);
    if ((t & 63) == 0) ws[t >> 6] = s;
    __syncthreads();
    if (t == 0) part[b] = ws[0] + ws[1] + ws[2] + ws[3];
}

__global__ void k_scan_small(const int* __restrict__ part, int* __restrict__ partScan) {
    __shared__ int sh[SNB];
    int t = threadIdx.x;
    if (t < SNB) sh[t] = part[t];
    __syncthreads();
    if (t < SNB) {
        int s = 0;
        for (int i = 0; i < t; i++) s += sh[i];
        partScan[t] = s;
    }
}

__global__ __launch_bounds__(256) void k_scan_emit(const int* __restrict__ cnt,
                                                   const int* __restrict__ partScan,
                                                   int* __restrict__ off,
                                                   int* __restrict__ cursor) {
    __shared__ int tsum[256];
    int b = blockIdx.x, t = threadIdx.x;
    int i0 = b * SCHUNK + t * 4;
    int e[4], p[4];
    int s = 0;
#pragma unroll
    for (int j = 0; j < 4; j++) {
        int i = i0 + j;
        e[j] = (i < NN) ? cnt[i] : 0;
        p[j] = s;
        s += e[j];
    }
    tsum[t] = s;
    __syncthreads();
    for (int d = 1; d < 256; d <<= 1) {
        int v = (t >= d) ? tsum[t - d] : 0;
        __syncthreads();
        tsum[t] += v;
        __syncthreads();
    }
    int base = partScan[b] + ((t == 0) ? 0 : tsum[t - 1]);
#pragma unroll
    for (int j = 0; j < 4; j++) {
        int i = i0 + j;
        if (i < NN) {
            int v = base + p[j];
            off[i] = v; cursor[i] = v;
            if (i == NN - 1) off[NN] = v + e[j];
        }
    }
}

// 8 dst-range groups; group = blockIdx&7 (XCD-affine).
#define SCAT_BPG 96
__global__ __launch_bounds__(256) void k_scatter_ids(
        const int* __restrict__ esrc, const int* __restrict__ edst,
        int* __restrict__ cursor, int* __restrict__ srcs) {
    const int grp = blockIdx.x & 7;
    const int blk = blockIdx.x >> 3;
    const int dlo = grp * (NN / 8), dhi = dlo + (NN / 8);
    for (int e = blk * 256 + threadIdx.x; e < NE; e += SCAT_BPG * 256) {
        int d = edst[e];
        if (d >= dlo && d < dhi) {
            int pos = atomicAdd(&cursor[d], 1);
            srcs[pos] = esrc[e];
        }
    }
}

// ---- per-graph node range from sorted batch ----
__global__ void k_bounds(const int* __restrict__ batch,
                         int* __restrict__ startg, int* __restrict__ endg) {
    int i = blockIdx.x * 256 + threadIdx.x;
    if (i >= NN) return;
    int g = batch[i];
    if (i == 0 || batch[i - 1] != g) startg[g] = i;
    if (i == NN - 1 || batch[i + 1] != g) endg[g] = i + 1;
}

// ---- weight pre-transpose: Wt[m][k][c] = Wm[c][k] ----
__global__ void k_wt(const float* __restrict__ Wl, const float* __restrict__ Wr,
                     const float* __restrict__ Rw, float* __restrict__ Wt, int din) {
    int i = blockIdx.x * 256 + threadIdx.x;
    if (i >= 3 * din * 64) return;
    int c = i & 63;
    int k = (i >> 6) & (din - 1);
    int m = i / (din * 64);
    const float* Wm = (m == 0) ? Wl : (m == 1) ? Wr : Rw;
    Wt[i] = Wm[c * din + k];
}

// ---- fused node GEMMs: BN=64, KC=32, 256 thr, 4ch x 4node, b128 x-reads ----
template <int DIN, bool RELU>
__global__ __launch_bounds__(256, 4) void k_gemm(
        const float* __restrict__ xin, const float* __restrict__ Wt,
        const float* __restrict__ bvec, const float* __restrict__ rb,
        float* __restrict__ xl, float* __restrict__ xr, float* __restrict__ acc) {
    constexpr int KC = 32;
    constexpr int LDX = KC + 4;            // 36: rows stay 16B-aligned
    __shared__ float xs[64 * LDX];         // 9.2 KB
    __shared__ float ws3[3 * KC * 64];     // 24 KB

    const int tid = threadIdx.x;
    const int cg = tid & 15;
    const int ng = tid >> 4;
    const int nb0 = blockIdx.x * 64;

    float4 al[4], ar[4], av[4];
#pragma unroll
    for (int i = 0; i < 4; i++) {
        al[i] = make_float4(0.f, 0.f, 0.f, 0.f);
        ar[i] = make_float4(0.f, 0.f, 0.f, 0.f);
        av[i] = make_float4(0.f, 0.f, 0.f, 0.f);
    }

    for (int c0 = 0; c0 < DIN; c0 += KC) {
        if (c0) __syncthreads();
        // x tile: 64 rows x 32 k = 512 float4, 2 per thread
        for (int q = tid; q < 64 * 8; q += 256) {
            int row = q >> 3, kq = q & 7;
            int n = nb0 + row;
            float4 v = make_float4(0.f, 0.f, 0.f, 0.f);
            if (n < NN) {
                v = *(const float4*)&xin[(size_t)n * DIN + c0 + 4 * kq];
                if (RELU) {
                    v.x = fmaxf(v.x, 0.f); v.y = fmaxf(v.y, 0.f);
                    v.z = fmaxf(v.z, 0.f); v.w = fmaxf(v.w, 0.f);
                }
            }
            *(float4*)&xs[row * LDX + 4 * kq] = v;
        }
        // W tiles: 3 x 32 k x 64 c = 1536 float4, 6 per thread
        for (int q = tid; q < 3 * KC * 16; q += 256) {
            int m = q >> 9, r = q & 511, kl = r >> 4, cq = r & 15;
            float4 v = *(const float4*)&Wt[(((size_t)m * DIN + c0 + kl) << 6) + 4 * cq];
            *(float4*)&ws3[(m * KC + kl) * 64 + 4 * cq] = v;
        }
        __syncthreads();

#pragma unroll
        for (int k4 = 0; k4 < KC; k4 += 4) {
            float4 xv[4];
#pragma unroll
            for (int i = 0; i < 4; i++)
                xv[i] = *(const float4*)&xs[(4 * ng + i) * LDX + k4];
#pragma unroll
            for (int kk = 0; kk < 4; kk++) {
                int k = k4 + kk;
                float4 w0 = *(const float4*)&ws3[(0 * KC + k) * 64 + 4 * cg];
                float4 w1 = *(const float4*)&ws3[(1 * KC + k) * 64 + 4 * cg];
                float4 w2 = *(const float4*)&ws3[(2 * KC + k) * 64 + 4 * cg];
#pragma unroll
                for (int i = 0; i < 4; i++) {
                    float xi = (&xv[i].x)[kk];
                    al[i].x += xi * w0.x; al[i].y += xi * w0.y; al[i].z += xi * w0.z; al[i].w += xi * w0.w;
                    ar[i].x += xi * w1.x; ar[i].y += xi * w1.y; ar[i].z += xi * w1.z; ar[i].w += xi * w1.w;
                    av[i].x += xi * w2.x; av[i].y += xi * w2.y; av[i].z += xi * w2.z; av[i].w += xi * w2.w;
                }
            }
        }
    }

    float4 b4 = ((const float4*)bvec)[cg];
    float4 r4 = ((const float4*)rb)[cg];
#pragma unroll
    for (int i = 0; i < 4; i++) {
        int n = nb0 + 4 * ng + i;
        if (n < NN) {
            ((float4*)&xl[(size_t)n * HID])[cg] = al[i];
            ((float4*)&xr[(size_t)n * HID])[cg] = ar[i];
            float4 o = av[i];
            o.x += b4.x + r4.x; o.y += b4.y + r4.y;
            o.z += b4.z + r4.z; o.w += b4.w + r4.w;
            ((float4*)&acc[(size_t)n * HID])[cg] = o;
        }
    }
}

// ---- fused per-dst attention: 8 edges x 8 channels per wave ----
__global__ __launch_bounds__(256) void k_attn_dst(
        const int* __restrict__ off, const int* __restrict__ srcs,
        const float* __restrict__ xl, const float* __restrict__ xr,
        const float* __restrict__ att, float* __restrict__ acc) {
    const int lane = threadIdx.x & 63;
    const int d = blockIdx.x * 4 + (threadIdx.x >> 6);
    if (d >= NN) return;
    const int e = lane >> 3;
    const int cg = lane & 7;

    const float4* xr4 = (const float4*)&xr[(size_t)d * HID + 8 * cg];
    float4 xra = xr4[0], xrb = xr4[1];
    const float4* at4 = (const float4*)&att[8 * cg];
    float4 ata = at4[0], atb = at4[1];

#define EDGE_LOGIT(S, XA, XB, T)                                               \
    {                                                                          \
        const float4* _x4 = (const float4*)&xl[(size_t)(S) * HID + 8 * cg];    \
        XA = _x4[0]; XB = _x4[1];                                              \
        float _ps;                                                             \
        float _v;                                                              \
        _v = XA.x + xra.x; _ps  = (fmaxf(_v,0.f) + NEG*fminf(_v,0.f)) * ata.x; \
        _v = XA.y + xra.y; _ps += (fmaxf(_v,0.f) + NEG*fminf(_v,0.f)) * ata.y; \
        _v = XA.z + xra.z; _ps += (fmaxf(_v,0.f) + NEG*fminf(_v,0.f)) * ata.z; \
        _v = XA.w + xra.w; _ps += (fmaxf(_v,0.f) + NEG*fminf(_v,0.f)) * ata.w; \
        _v = XB.x + xrb.x; _ps += (fmaxf(_v,0.f) + NEG*fminf(_v,0.f)) * atb.x; \
        _v = XB.y + xrb.y; _ps += (fmaxf(_v,0.f) + NEG*fminf(_v,0.f)) * atb.y; \
        _v = XB.z + xrb.z; _ps += (fmaxf(_v,0.f) + NEG*fminf(_v,0.f)) * atb.z; \
        _v = XB.w + xrb.w; _ps += (fmaxf(_v,0.f) + NEG*fminf(_v,0.f)) * atb.w; \
        _ps += __shfl_xor(_ps, 1, 64);                                         \
        _ps += __shfl_xor(_ps, 2, 64);                                         \
        _ps += __shfl_xor(_ps, 4, 64);                                         \
        T = _ps;                                                               \
    }

    float m, l;
    float4 oA, oB;
    {
        float4 xla, xlb; float t;
        EDGE_LOGIT(d, xla, xlb, t);
        m = t;
        bool own = (e == 0);
        l = own ? 1.f : 0.f;
        oA = own ? xla : make_float4(0.f, 0.f, 0.f, 0.f);
        oB = own ? xlb : make_float4(0.f, 0.f, 0.f, 0.f);
    }

    const int lo = off[d], deg = off[d + 1] - lo;
    for (int base = 0; base < deg; base += 8) {
        int nv = deg - base;
        int sv = 0;
        if (lane < 8) sv = srcs[lo + min(base + lane, deg - 1)];
        int s = __shfl(sv, e, 64);

        float4 xla, xlb; float t;
        EDGE_LOGIT(s, xla, xlb, t);
        if (e >= nv) t = -INFINITY;

        float cm = t;
        cm = fmaxf(cm, __shfl_xor(cm, 8, 64));
        cm = fmaxf(cm, __shfl_xor(cm, 16, 64));
        cm = fmaxf(cm, __shfl_xor(cm, 32, 64));
        float newm = fmaxf(m, cm);
        float corr = __expf(m - newm);
        float p = __expf(t - newm);
        m = newm;
        l = l * corr + p;
        oA.x = oA.x * corr + p * xla.x; oA.y = oA.y * corr + p * xla.y;
        oA.z = oA.z * corr + p * xla.z; oA.w = oA.w * corr + p * xla.w;
        oB.x = oB.x * corr + p * xlb.x; oB.y = oB.y * corr + p * xlb.y;
        oB.z = oB.z * corr + p * xlb.z; oB.w = oB.w * corr + p * xlb.w;
    }
#undef EDGE_LOGIT

#pragma unroll
    for (int w = 8; w <= 32; w <<= 1) {
        l    += __shfl_xor(l, w, 64);
        oA.x += __shfl_xor(oA.x, w, 64); oA.y += __shfl_xor(oA.y, w, 64);
        oA.z += __shfl_xor(oA.z, w, 64); oA.w += __shfl_xor(oA.w, w, 64);
        oB.x += __shfl_xor(oB.x, w, 64); oB.y += __shfl_xor(oB.y, w, 64);
        oB.z += __shfl_xor(oB.z, w, 64); oB.w += __shfl_xor(oB.w, w, 64);
    }

    if (e == 0) {
        float inv = 1.f / l;
        float4* a4 = (float4*)&acc[(size_t)d * HID + 8 * cg];
        float4 c0 = a4[0], c1 = a4[1];
        c0.x += oA.x * inv; c0.y += oA.y * inv;
        c0.z += oA.z * inv; c0.w += oA.w * inv;
        c1.x += oB.x * inv; c1.y += oB.y * inv;
        c1.z += oB.z * inv; c1.w += oB.w * inv;
        a4[0] = c0; a4[1] = c1;
    }
}

// ---- fused mean-pool + head: one block (512 thr) per graph ----
__global__ __launch_bounds__(512) void k_pool_final(
        const float* __restrict__ acc,
        const int* __restrict__ startg, const int* __restrict__ endg,
        const float* __restrict__ Wf, const float* __restrict__ bf_,
        float* __restrict__ out) {
    __shared__ float red[8][HID];
    const int g = blockIdx.x;
    const int c = threadIdx.x & 63;
    const int j = threadIdx.x >> 6;
    const int s = startg[g], epos = endg[g];

    float sum = 0.f;
    for (int n = s + j; n < epos; n += 8)
        sum += acc[(size_t)n * HID + c];
    red[j][c] = sum;
    __syncthreads();

    if (threadIdx.x < HID) {
        float tot = 0.f;
#pragma unroll
        for (int w = 0; w < 8; w++) tot += red[w][c];
        float cntf = (float)(epos - s);
        float v = tot / fmaxf(cntf, 1.f) * Wf[c];
#pragma unroll
        for (int o = 32; o; o >>= 1) v += __shfl_xor(v, o, 64);
        if (c == 0) out[g] = v + bf_[0];
    }
}

extern "C" void kernel_launch(void* const* d_in, const int* in_sizes, int n_in,
                              void* d_out, int out_size, void* d_ws, size_t ws_size,
                              hipStream_t stream) {
    const float* x   = (const float*)d_in[0];
    const int* eidx  = (const int*)d_in[1];
    const int* batch = (const int*)d_in[2];
    const int* esrc = eidx;
    const int* edst = eidx + NE;
    const float* Wf  = (const float*)d_in[21];
    const float* bfb = (const float*)d_in[22];

    float* wsf = (float*)d_ws;
    const size_t NN64 = (size_t)NN * HID;
    float* xl     = wsf;
    float* xr     = xl + NN64;
    float* acc0   = xr + NN64;
    float* acc1   = acc0 + NN64;
    int*   ccnt   = (int*)(acc1 + NN64);
    int*   startg = ccnt + NN;
    int*   endg   = startg + NG;
    int*   off    = endg + NG;
    int*   cursor = off + NN + 1;
    int*   part   = cursor + NN;
    int*   partSc = part + SNB;
    int*   srcs   = partSc + SNB;
    float* Wt0    = (float*)(srcs + NE);
    float* Wt1    = Wt0 + 3 * DIN0 * HID;
    float* Wt2    = Wt1 + 3 * HID * HID;
    float* Wts[3] = {Wt0, Wt1, Wt2};

    // weight pre-transpose (tiny) + CSR build + graph bounds
    k_wt<<<(3 * DIN0 * HID + 255) / 256, 256, 0, stream>>>(
        (const float*)d_in[3], (const float*)d_in[4], (const float*)d_in[7], Wt0, DIN0);
    k_wt<<<(3 * HID * HID + 255) / 256, 256, 0, stream>>>(
        (const float*)d_in[9], (const float*)d_in[10], (const float*)d_in[13], Wt1, HID);
    k_wt<<<(3 * HID * HID + 255) / 256, 256, 0, stream>>>(
        (const float*)d_in[15], (const float*)d_in[16], (const float*)d_in[19], Wt2, HID);

    k_zero_int<<<(NN + 2 * NG + 255) / 256, 256, 0, stream>>>(ccnt, NN + 2 * NG);
    k_hist<<<(NE + 255) / 256, 256, 0, stream>>>(edst, ccnt);
    k_scan_part<<<SNB, 256, 0, stream>>>(ccnt, part);
    k_scan_small<<<1, 64, 0, stream>>>(part, partSc);
    k_scan_emit<<<SNB, 256, 0, stream>>>(ccnt, partSc, off, cursor);
    k_scatter_ids<<<8 * SCAT_BPG, 256, 0, stream>>>(esrc, edst, cursor, srcs);
    k_bounds<<<(NN + 255) / 256, 256, 0, stream>>>(batch, startg, endg);

    float* accs[4] = {acc0, acc0, acc1, acc0};  // out of layer L = accs[L+1]
    const int gemm_grid = (NN + 63) / 64;
    for (int L = 0; L < 3; L++) {
        const float* att = (const float*)d_in[3 + L * 6 + 2];
        const float* b   = (const float*)d_in[3 + L * 6 + 3];
        const float* Rb  = (const float*)d_in[3 + L * 6 + 5];
        float* accOut = accs[L + 1];

        if (L == 0)
            k_gemm<DIN0, false><<<gemm_grid, 256, 0, stream>>>(
                x, Wts[0], b, Rb, xl, xr, accOut);
        else
            k_gemm<HID, true><<<gemm_grid, 256, 0, stream>>>(
                accs[L], Wts[L], b, Rb, xl, xr, accOut);

        k_attn_dst<<<(NN + 3) / 4, 256, 0, stream>>>(off, srcs, xl, xr, att, accOut);
    }

    k_pool_final<<<NG, 512, 0, stream>>>(accs[3], startg, endg, Wf, bfb, (float*)d_out);
}

// Round 15
// 451.754 us; speedup vs baseline: 1.1750x; 1.1750x over previous
//
#include <hip/hip_runtime.h>

// GATv2 3-layer + mean-pool + linear head, MI355X.
// R14: strict revert to the measured-best R11-bench config (460us: gemm v4
// BN=64/KC=32/LDX=33/4x4/lb(256,4); simple 8-group scatter). R13's k4-blocked
// gemm spilled (VGPR 64, WRITE 171MB of scratch traffic). Adds only:
// (1) XCD-sliced histogram cnt8[8][NN] + reduce (same-line atomic collisions /8)
// (2) merged setup launches (k_wt_all, k_bounds zeroes cnt8).

#define NN 50000
#define NE 1000000
#define HID 64
#define DIN0 128
#define NG 256
#define NEG 0.2f

#define SCHUNK 1024
#define SNB ((NN + SCHUNK - 1) / SCHUNK)   // 49 blocks

// ---- merged weight pre-transpose (all 3 layers) + zero startg/endg ----
// Wt layout per layer: [m][k][c], m in {Wl,Wr,Rw}
__global__ __launch_bounds__(256) void k_wt_all(
        const float* __restrict__ Wl0, const float* __restrict__ Wr0, const float* __restrict__ Rw0,
        const float* __restrict__ Wl1, const float* __restrict__ Wr1, const float* __restrict__ Rw1,
        const float* __restrict__ Wl2, const float* __restrict__ Wr2, const float* __restrict__ Rw2,
        float* __restrict__ Wt0, float* __restrict__ Wt1, float* __restrict__ Wt2,
        int* __restrict__ startg, int* __restrict__ endg) {
    int i = blockIdx.x * 256 + threadIdx.x;
    if (i < 2 * NG) {
        if (i < NG) startg[i] = 0; else endg[i - NG] = 0;
    }
    const int L0N = 3 * DIN0 * HID;          // 24576
    const int L1N = 3 * HID * HID;           // 12288
    if (i >= L0N + 2 * L1N) return;
    const float* Wm; float* Wt; int din, local;
    if (i < L0N) {
        local = i; din = DIN0; Wt = Wt0;
        int m = local / (DIN0 * HID);
        Wm = (m == 0) ? Wl0 : (m == 1) ? Wr0 : Rw0;
    } else if (i < L0N + L1N) {
        local = i - L0N; din = HID; Wt = Wt1;
        int m = local / (HID * HID);
        Wm = (m == 0) ? Wl1 : (m == 1) ? Wr1 : Rw1;
    } else {
        local = i - L0N - L1N; din = HID; Wt = Wt2;
        int m = local / (HID * HID);
        Wm = (m == 0) ? Wl2 : (m == 1) ? Wr2 : Rw2;
    }
    int r = local % (din * HID);
    int c = r & 63;
    int k = r >> 6;
    Wt[local] = Wm[c * din + k];
}

// ---- graph bounds from sorted batch + zero the 8 histogram slices ----
__global__ void k_bounds(const int* __restrict__ batch,
                         int* __restrict__ startg, int* __restrict__ endg,
                         int* __restrict__ cnt8) {
    int i = blockIdx.x * 256 + threadIdx.x;
    if (i >= NN) return;
#pragma unroll
    for (int g = 0; g < 8; g++) cnt8[g * NN + i] = 0;
    int g = batch[i];
    if (i == 0 || batch[i - 1] != g) startg[g] = i;
    if (i == NN - 1 || batch[i + 1] != g) endg[g] = i + 1;
}

// ---- XCD-sliced histogram: slice = blockIdx&7 ----
__global__ __launch_bounds__(256) void k_hist8(const int* __restrict__ edst,
                                               int* __restrict__ cnt8) {
    int* mycnt = cnt8 + (blockIdx.x & 7) * NN;
    for (int e = blockIdx.x * 256 + threadIdx.x; e < NE; e += 512 * 256)
        atomicAdd(&mycnt[edst[e]], 1);
}

__global__ void k_hist_red(const int* __restrict__ cnt8, int* __restrict__ cnt) {
    int i = blockIdx.x * 256 + threadIdx.x;
    if (i >= NN) return;
    int s = 0;
#pragma unroll
    for (int g = 0; g < 8; g++) s += cnt8[g * NN + i];
    cnt[i] = s;
}

// ---- scan over dst counts (3-phase) ----
__global__ __launch_bounds__(256) void k_scan_part(const int* __restrict__ cnt,
                                                   int* __restrict__ part) {
    __shared__ int ws[4];
    int b = blockIdx.x, t = threadIdx.x;
    int i0 = b * SCHUNK + t * 4;
    int s = 0;
#pragma unroll
    for (int j = 0; j < 4; j++) {
        int i = i0 + j;
        if (i < NN) s += cnt[i];
    }
#pragma unroll
    for (int o = 32; o; o >>= 1) s += __shfl_xor(s, o, 64);
    if ((t & 63) == 0) ws[t >> 6] = s;
    __syncthreads();
    if (t == 0) part[b] = ws[0] + ws[1] + ws[2] + ws[3];
}

__global__ void k_scan_small(const int* __restrict__ part, int* __restrict__ partScan) {
    __shared__ int sh[SNB];
    int t = threadIdx.x;
    if (t < SNB) sh[t] = part[t];
    __syncthreads();
    if (t < SNB) {
        int s = 0;
        for (int i = 0; i < t; i++) s += sh[i];
        partScan[t] = s;
    }
}

__global__ __launch_bounds__(256) void k_scan_emit(const int* __restrict__ cnt,
                                                   const int* __restrict__ partScan,
                                                   int* __restrict__ off,
                                                   int* __restrict__ cursor) {
    __shared__ int tsum[256];
    int b = blockIdx.x, t = threadIdx.x;
    int i0 = b * SCHUNK + t * 4;
    int e[4], p[4];
    int s = 0;
#pragma unroll
    for (int j = 0; j < 4; j++) {
        int i = i0 + j;
        e[j] = (i < NN) ? cnt[i] : 0;
        p[j] = s;
        s += e[j];
    }
    tsum[t] = s;
    __syncthreads();
    for (int d = 1; d < 256; d <<= 1) {
        int v = (t >= d) ? tsum[t - d] : 0;
        __syncthreads();
        tsum[t] += v;
        __syncthreads();
    }
    int base = partScan[b] + ((t == 0) ? 0 : tsum[t - 1]);
#pragma unroll
    for (int j = 0; j < 4; j++) {
        int i = i0 + j;
        if (i < NN) {
            int v = base + p[j];
            off[i] = v; cursor[i] = v;
            if (i == NN - 1) off[NN] = v + e[j];
        }
    }
}

// 8 dst-range groups; group = blockIdx&7 (XCD-affine).
#define SCAT_BPG 96
__global__ __launch_bounds__(256) void k_scatter_ids(
        const int* __restrict__ esrc, const int* __restrict__ edst,
        int* __restrict__ cursor, int* __restrict__ srcs) {
    const int grp = blockIdx.x & 7;
    const int blk = blockIdx.x >> 3;
    const int dlo = grp * (NN / 8), dhi = dlo + (NN / 8);
    for (int e = blk * 256 + threadIdx.x; e < NE; e += SCAT_BPG * 256) {
        int d = edst[e];
        if (d >= dlo && d < dhi) {
            int pos = atomicAdd(&cursor[d], 1);
            srcs[pos] = esrc[e];
        }
    }
}

// ---- fused node GEMMs (measured-best): BN=64, KC=32, 256 thr, 4ch x 4node ----
template <int DIN, bool RELU>
__global__ __launch_bounds__(256, 4) void k_gemm(
        const float* __restrict__ xin, const float* __restrict__ Wt,
        const float* __restrict__ bvec, const float* __restrict__ rb,
        float* __restrict__ xl, float* __restrict__ xr, float* __restrict__ acc) {
    constexpr int KC = 32;
    constexpr int LDX = KC + 1;            // 33
    __shared__ float xs[64 * LDX];         // 8.4 KB
    __shared__ float ws3[3 * KC * 64];     // 24 KB

    const int tid = threadIdx.x;
    const int cg = tid & 15;
    const int ng = tid >> 4;
    const int nb0 = blockIdx.x * 64;

    float4 al[4], ar[4], av[4];
#pragma unroll
    for (int i = 0; i < 4; i++) {
        al[i] = make_float4(0.f, 0.f, 0.f, 0.f);
        ar[i] = make_float4(0.f, 0.f, 0.f, 0.f);
        av[i] = make_float4(0.f, 0.f, 0.f, 0.f);
    }

    for (int c0 = 0; c0 < DIN; c0 += KC) {
        if (c0) __syncthreads();
        for (int q = tid; q < 64 * 8; q += 256) {
            int row = q >> 3, kq = q & 7;
            int n = nb0 + row;
            float4 v = make_float4(0.f, 0.f, 0.f, 0.f);
            if (n < NN) {
                v = *(const float4*)&xin[(size_t)n * DIN + c0 + 4 * kq];
                if (RELU) {
                    v.x = fmaxf(v.x, 0.f); v.y = fmaxf(v.y, 0.f);
                    v.z = fmaxf(v.z, 0.f); v.w = fmaxf(v.w, 0.f);
                }
            }
            *(float4*)&xs[row * LDX + 4 * kq] = v;
        }
        for (int q = tid; q < 3 * KC * 16; q += 256) {
            int m = q >> 9, r = q & 511, kl = r >> 4, cq = r & 15;
            float4 v = *(const float4*)&Wt[(((size_t)m * DIN + c0 + kl) << 6) + 4 * cq];
            *(float4*)&ws3[(m * KC + kl) * 64 + 4 * cq] = v;
        }
        __syncthreads();

#pragma unroll 4
        for (int k = 0; k < KC; k++) {
            float4 w0 = *(const float4*)&ws3[(0 * KC + k) * 64 + 4 * cg];
            float4 w1 = *(const float4*)&ws3[(1 * KC + k) * 64 + 4 * cg];
            float4 w2 = *(const float4*)&ws3[(2 * KC + k) * 64 + 4 * cg];
#pragma unroll
            for (int i = 0; i < 4; i++) {
                float xi = xs[(4 * ng + i) * LDX + k];
                al[i].x += xi * w0.x; al[i].y += xi * w0.y; al[i].z += xi * w0.z; al[i].w += xi * w0.w;
                ar[i].x += xi * w1.x; ar[i].y += xi * w1.y; ar[i].z += xi * w1.z; ar[i].w += xi * w1.w;
                av[i].x += xi * w2.x; av[i].y += xi * w2.y; av[i].z += xi * w2.z; av[i].w += xi * w2.w;
            }
        }
    }

    float4 b4 = ((const float4*)bvec)[cg];
    float4 r4 = ((const float4*)rb)[cg];
#pragma unroll
    for (int i = 0; i < 4; i++) {
        int n = nb0 + 4 * ng + i;
        if (n < NN) {
            ((float4*)&xl[(size_t)n * HID])[cg] = al[i];
            ((float4*)&xr[(size_t)n * HID])[cg] = ar[i];
            float4 o = av[i];
            o.x += b4.x + r4.x; o.y += b4.y + r4.y;
            o.z += b4.z + r4.z; o.w += b4.w + r4.w;
            ((float4*)&acc[(size_t)n * HID])[cg] = o;
        }
    }
}

// ---- fused per-dst attention: 8 edges x 8 channels per wave ----
__global__ __launch_bounds__(256) void k_attn_dst(
        const int* __restrict__ off, const int* __restrict__ srcs,
        const float* __restrict__ xl, const float* __restrict__ xr,
        const float* __restrict__ att, float* __restrict__ acc) {
    const int lane = threadIdx.x & 63;
    const int d = blockIdx.x * 4 + (threadIdx.x >> 6);
    if (d >= NN) return;
    const int e = lane >> 3;
    const int cg = lane & 7;

    const float4* xr4 = (const float4*)&xr[(size_t)d * HID + 8 * cg];
    float4 xra = xr4[0], xrb = xr4[1];
    const float4* at4 = (const float4*)&att[8 * cg];
    float4 ata = at4[0], atb = at4[1];

#define EDGE_LOGIT(S, XA, XB, T)                                               \
    {                                                                          \
        const float4* _x4 = (const float4*)&xl[(size_t)(S) * HID + 8 * cg];    \
        XA = _x4[0]; XB = _x4[1];                                              \
        float _ps;                                                             \
        float _v;                                                              \
        _v = XA.x + xra.x; _ps  = (fmaxf(_v,0.f) + NEG*fminf(_v,0.f)) * ata.x; \
        _v = XA.y + xra.y; _ps += (fmaxf(_v,0.f) + NEG*fminf(_v,0.f)) * ata.y; \
        _v = XA.z + xra.z; _ps += (fmaxf(_v,0.f) + NEG*fminf(_v,0.f)) * ata.z; \
        _v = XA.w + xra.w; _ps += (fmaxf(_v,0.f) + NEG*fminf(_v,0.f)) * ata.w; \
        _v = XB.x + xrb.x; _ps += (fmaxf(_v,0.f) + NEG*fminf(_v,0.f)) * atb.x; \
        _v = XB.y + xrb.y; _ps += (fmaxf(_v,0.f) + NEG*fminf(_v,0.f)) * atb.y; \
        _v = XB.z + xrb.z; _ps += (fmaxf(_v,0.f) + NEG*fminf(_v,0.f)) * atb.z; \
        _v = XB.w + xrb.w; _ps += (fmaxf(_v,0.f) + NEG*fminf(_v,0.f)) * atb.w; \
        _ps += __shfl_xor(_ps, 1, 64);                                         \
        _ps += __shfl_xor(_ps, 2, 64);                                         \
        _ps += __shfl_xor(_ps, 4, 64);                                         \
        T = _ps;                                                               \
    }

    float m, l;
    float4 oA, oB;
    {
        float4 xla, xlb; float t;
        EDGE_LOGIT(d, xla, xlb, t);
        m = t;
        bool own = (e == 0);
        l = own ? 1.f : 0.f;
        oA = own ? xla : make_float4(0.f, 0.f, 0.f, 0.f);
        oB = own ? xlb : make_float4(0.f, 0.f, 0.f, 0.f);
    }

    const int lo = off[d], deg = off[d + 1] - lo;
    for (int base = 0; base < deg; base += 8) {
        int nv = deg - base;
        int sv = 0;
        if (lane < 8) sv = srcs[lo + min(base + lane, deg - 1)];
        int s = __shfl(sv, e, 64);

        float4 xla, xlb; float t;
        EDGE_LOGIT(s, xla, xlb, t);
        if (e >= nv) t = -INFINITY;

        float cm = t;
        cm = fmaxf(cm, __shfl_xor(cm, 8, 64));
        cm = fmaxf(cm, __shfl_xor(cm, 16, 64));
        cm = fmaxf(cm, __shfl_xor(cm, 32, 64));
        float newm = fmaxf(m, cm);
        float corr = __expf(m - newm);
        float p = __expf(t - newm);
        m = newm;
        l = l * corr + p;
        oA.x = oA.x * corr + p * xla.x; oA.y = oA.y * corr + p * xla.y;
        oA.z = oA.z * corr + p * xla.z; oA.w = oA.w * corr + p * xla.w;
        oB.x = oB.x * corr + p * xlb.x; oB.y = oB.y * corr + p * xlb.y;
        oB.z = oB.z * corr + p * xlb.z; oB.w = oB.w * corr + p * xlb.w;
    }
#undef EDGE_LOGIT

#pragma unroll
    for (int w = 8; w <= 32; w <<= 1) {
        l    += __shfl_xor(l, w, 64);
        oA.x += __shfl_xor(oA.x, w, 64); oA.y += __shfl_xor(oA.y, w, 64);
        oA.z += __shfl_xor(oA.z, w, 64); oA.w += __shfl_xor(oA.w, w, 64);
        oB.x += __shfl_xor(oB.x, w, 64); oB.y += __shfl_xor(oB.y, w, 64);
        oB.z += __shfl_xor(oB.z, w, 64); oB.w += __shfl_xor(oB.w, w, 64);
    }

    if (e == 0) {
        float inv = 1.f / l;
        float4* a4 = (float4*)&acc[(size_t)d * HID + 8 * cg];
        float4 c0 = a4[0], c1 = a4[1];
        c0.x += oA.x * inv; c0.y += oA.y * inv;
        c0.z += oA.z * inv; c0.w += oA.w * inv;
        c1.x += oB.x * inv; c1.y += oB.y * inv;
        c1.z += oB.z * inv; c1.w += oB.w * inv;
        a4[0] = c0; a4[1] = c1;
    }
}

// ---- fused mean-pool + head: one block (512 thr) per graph ----
__global__ __launch_bounds__(512) void k_pool_final(
        const float* __restrict__ acc,
        const int* __restrict__ startg, const int* __restrict__ endg,
        const float* __restrict__ Wf, const float* __restrict__ bf_,
        float* __restrict__ out) {
    __shared__ float red[8][HID];
    const int g = blockIdx.x;
    const int c = threadIdx.x & 63;
    const int j = threadIdx.x >> 6;
    const int s = startg[g], epos = endg[g];

    float sum = 0.f;
    for (int n = s + j; n < epos; n += 8)
        sum += acc[(size_t)n * HID + c];
    red[j][c] = sum;
    __syncthreads();

    if (threadIdx.x < HID) {
        float tot = 0.f;
#pragma unroll
        for (int w = 0; w < 8; w++) tot += red[w][c];
        float cntf = (float)(epos - s);
        float v = tot / fmaxf(cntf, 1.f) * Wf[c];
#pragma unroll
        for (int o = 32; o; o >>= 1) v += __shfl_xor(v, o, 64);
        if (c == 0) out[g] = v + bf_[0];
    }
}

extern "C" void kernel_launch(void* const* d_in, const int* in_sizes, int n_in,
                              void* d_out, int out_size, void* d_ws, size_t ws_size,
                              hipStream_t stream) {
    const float* x   = (const float*)d_in[0];
    const int* eidx  = (const int*)d_in[1];
    const int* batch = (const int*)d_in[2];
    const int* esrc = eidx;
    const int* edst = eidx + NE;
    const float* Wf  = (const float*)d_in[21];
    const float* bfb = (const float*)d_in[22];

    float* wsf = (float*)d_ws;
    const size_t NN64 = (size_t)NN * HID;
    float* xl     = wsf;
    float* xr     = xl + NN64;
    float* acc0   = xr + NN64;
    float* acc1   = acc0 + NN64;
    int*   ccnt   = (int*)(acc1 + NN64);
    int*   startg = ccnt + NN;
    int*   endg   = startg + NG;
    int*   off    = endg + NG;
    int*   cursor = off + NN + 1;
    int*   part   = cursor + NN;
    int*   partSc = part + SNB;
    int*   cnt8   = partSc + SNB;          // 8*NN
    int*   srcs   = cnt8 + 8 * NN;
    float* Wt0    = (float*)(srcs + NE);
    float* Wt1    = Wt0 + 3 * DIN0 * HID;
    float* Wt2    = Wt1 + 3 * HID * HID;
    float* Wts[3] = {Wt0, Wt1, Wt2};

    // setup: merged weight transpose (+zero startg/endg), bounds (+zero cnt8)
    k_wt_all<<<(3 * DIN0 * HID + 2 * 3 * HID * HID + 255) / 256, 256, 0, stream>>>(
        (const float*)d_in[3], (const float*)d_in[4], (const float*)d_in[7],
        (const float*)d_in[9], (const float*)d_in[10], (const float*)d_in[13],
        (const float*)d_in[15], (const float*)d_in[16], (const float*)d_in[19],
        Wt0, Wt1, Wt2, startg, endg);
    k_bounds<<<(NN + 255) / 256, 256, 0, stream>>>(batch, startg, endg, cnt8);

    // CSR build
    k_hist8<<<512, 256, 0, stream>>>(edst, cnt8);
    k_hist_red<<<(NN + 255) / 256, 256, 0, stream>>>(cnt8, ccnt);
    k_scan_part<<<SNB, 256, 0, stream>>>(ccnt, part);
    k_scan_small<<<1, 64, 0, stream>>>(part, partSc);
    k_scan_emit<<<SNB, 256, 0, stream>>>(ccnt, partSc, off, cursor);
    k_scatter_ids<<<8 * SCAT_BPG, 256, 0, stream>>>(esrc, edst, cursor, srcs);

    float* accs[4] = {acc0, acc0, acc1, acc0};  // out of layer L = accs[L+1]
    const int gemm_grid = (NN + 63) / 64;
    for (int L = 0; L < 3; L++) {
        const float* att = (const float*)d_in[3 + L * 6 + 2];
        const float* b   = (const float*)d_in[3 + L * 6 + 3];
        const float* Rb  = (const float*)d_in[3 + L * 6 + 5];
        float* accOut = accs[L + 1];

        if (L == 0)
            k_gemm<DIN0, false><<<gemm_grid, 256, 0, stream>>>(
                x, Wts[0], b, Rb, xl, xr, accOut);
        else
            k_gemm<HID, true><<<gemm_grid, 256, 0, stream>>>(
                accs[L], Wts[L], b, Rb, xl, xr, accOut);

        k_attn_dst<<<(NN + 3) / 4, 256, 0, stream>>>(off, srcs, xl, xr, att, accOut);
    }

    k_pool_final<<<NG, 512, 0, stream>>>(accs[3], startg, endg, Wf, bfb, (float*)d_out);
}

// Round 17
// 413.442 us; speedup vs baseline: 1.2838x; 1.0927x over previous
//
#include <hip/hip_runtime.h>

// GATv2 3-layer + mean-pool + linear head, MI355X.
// R16: R15's MFMA gemm with the compile fix (split_bf returned into scalar
// locals — clang can't bind non-const refs to ext_vector elements).
// gemm = mfma_f32_16x16x32_bf16, split-precision hi+lo (hh+hl+lh).

#define NN 50000
#define NE 1000000
#define HID 64
#define DIN0 128
#define NG 256
#define NEG 0.2f

#define SCHUNK 1024
#define SNB ((NN + SCHUNK - 1) / SCHUNK)   // 49 blocks

typedef float f32x4 __attribute__((ext_vector_type(4)));
typedef short s8v __attribute__((ext_vector_type(8)));
typedef short s4v __attribute__((ext_vector_type(4)));
typedef __bf16 bf16x8 __attribute__((ext_vector_type(8)));

__device__ __forceinline__ unsigned short f2bf(float f) {
    unsigned u = __float_as_uint(f);
    u = u + 0x7fffu + ((u >> 16) & 1u);   // RNE
    return (unsigned short)(u >> 16);
}
__device__ __forceinline__ float bf2f(unsigned short v) {
    return __uint_as_float(((unsigned)v) << 16);
}
__device__ __forceinline__ short split_hi(float x) {
    return (short)f2bf(x);
}
__device__ __forceinline__ short split_lo(float x, short hi) {
    return (short)f2bf(x - bf2f((unsigned short)hi));
}

// ---- merged weight pre-split (all 3 layers) + zero startg/endg ----
// Ws layout per layer (shorts): [(mat*2+plane)][c][k] row-major k, mat in {Wl,Wr,Rw}
__global__ __launch_bounds__(256) void k_wt_all(
        const float* __restrict__ Wl0, const float* __restrict__ Wr0, const float* __restrict__ Rw0,
        const float* __restrict__ Wl1, const float* __restrict__ Wr1, const float* __restrict__ Rw1,
        const float* __restrict__ Wl2, const float* __restrict__ Wr2, const float* __restrict__ Rw2,
        short* __restrict__ Ws0, short* __restrict__ Ws1, short* __restrict__ Ws2,
        int* __restrict__ startg, int* __restrict__ endg) {
    int i = blockIdx.x * 256 + threadIdx.x;
    if (i < 2 * NG) {
        if (i < NG) startg[i] = 0; else endg[i - NG] = 0;
    }
    const int L0N = 3 * HID * DIN0;          // 24576 source elems
    const int L1N = 3 * HID * HID;           // 12288
    if (i >= L0N + 2 * L1N) return;
    const float* Wm; short* Ws; int din, local;
    if (i < L0N) {
        local = i; din = DIN0; Ws = Ws0;
        int m = local / (DIN0 * HID);
        Wm = (m == 0) ? Wl0 : (m == 1) ? Wr0 : Rw0;
    } else if (i < L0N + L1N) {
        local = i - L0N; din = HID; Ws = Ws1;
        int m = local / (HID * HID);
        Wm = (m == 0) ? Wl1 : (m == 1) ? Wr1 : Rw1;
    } else {
        local = i - L0N - L1N; din = HID; Ws = Ws2;
        int m = local / (HID * HID);
        Wm = (m == 0) ? Wl2 : (m == 1) ? Wr2 : Rw2;
    }
    int m = local / (din * HID);
    int r = local - m * (din * HID);        // r = c*din + k
    int c = r / din, k = r - c * din;
    float w = Wm[c * din + k];
    short hi = split_hi(w);
    short lo = split_lo(w, hi);
    Ws[(((m * 2 + 0) * HID + c) * din) + k] = hi;
    Ws[(((m * 2 + 1) * HID + c) * din) + k] = lo;
}

// ---- graph bounds from sorted batch + zero the 8 histogram slices ----
__global__ void k_bounds(const int* __restrict__ batch,
                         int* __restrict__ startg, int* __restrict__ endg,
                         int* __restrict__ cnt8) {
    int i = blockIdx.x * 256 + threadIdx.x;
    if (i >= NN) return;
#pragma unroll
    for (int g = 0; g < 8; g++) cnt8[g * NN + i] = 0;
    int g = batch[i];
    if (i == 0 || batch[i - 1] != g) startg[g] = i;
    if (i == NN - 1 || batch[i + 1] != g) endg[g] = i + 1;
}

// ---- XCD-sliced histogram ----
__global__ __launch_bounds__(256) void k_hist8(const int* __restrict__ edst,
                                               int* __restrict__ cnt8) {
    int* mycnt = cnt8 + (blockIdx.x & 7) * NN;
    for (int e = blockIdx.x * 256 + threadIdx.x; e < NE; e += 512 * 256)
        atomicAdd(&mycnt[edst[e]], 1);
}

__global__ void k_hist_red(const int* __restrict__ cnt8, int* __restrict__ cnt) {
    int i = blockIdx.x * 256 + threadIdx.x;
    if (i >= NN) return;
    int s = 0;
#pragma unroll
    for (int g = 0; g < 8; g++) s += cnt8[g * NN + i];
    cnt[i] = s;
}

// ---- scan over dst counts (3-phase) ----
__global__ __launch_bounds__(256) void k_scan_part(const int* __restrict__ cnt,
                                                   int* __restrict__ part) {
    __shared__ int ws[4];
    int b = blockIdx.x, t = threadIdx.x;
    int i0 = b * SCHUNK + t * 4;
    int s = 0;
#pragma unroll
    for (int j = 0; j < 4; j++) {
        int i = i0 + j;
        if (i < NN) s += cnt[i];
    }
#pragma unroll
    for (int o = 32; o; o >>= 1) s += __shfl_xor(s, o, 64);
    if ((t & 63) == 0) ws[t >> 6] = s;
    __syncthreads();
    if (t == 0) part[b] = ws[0] + ws[1] + ws[2] + ws[3];
}

__global__ void k_scan_small(const int* __restrict__ part, int* __restrict__ partScan) {
    __shared__ int sh[SNB];
    int t = threadIdx.x;
    if (t < SNB) sh[t] = part[t];
    __syncthreads();
    if (t < SNB) {
        int s = 0;
        for (int i = 0; i < t; i++) s += sh[i];
        partScan[t] = s;
    }
}

__global__ __launch_bounds__(256) void k_scan_emit(const int* __restrict__ cnt,
                                                   const int* __restrict__ partScan,
                                                   int* __restrict__ off,
                                                   int* __restrict__ cursor) {
    __shared__ int tsum[256];
    int b = blockIdx.x, t = threadIdx.x;
    int i0 = b * SCHUNK + t * 4;
    int e[4], p[4];
    int s = 0;
#pragma unroll
    for (int j = 0; j < 4; j++) {
        int i = i0 + j;
        e[j] = (i < NN) ? cnt[i] : 0;
        p[j] = s;
        s += e[j];
    }
    tsum[t] = s;
    __syncthreads();
    for (int d = 1; d < 256; d <<= 1) {
        int v = (t >= d) ? tsum[t - d] : 0;
        __syncthreads();
        tsum[t] += v;
        __syncthreads();
    }
    int base = partScan[b] + ((t == 0) ? 0 : tsum[t - 1]);
#pragma unroll
    for (int j = 0; j < 4; j++) {
        int i = i0 + j;
        if (i < NN) {
            int v = base + p[j];
            off[i] = v; cursor[i] = v;
            if (i == NN - 1) off[NN] = v + e[j];
        }
    }
}

// 8 dst-range groups; group = blockIdx&7 (XCD-affine).
#define SCAT_BPG 96
__global__ __launch_bounds__(256) void k_scatter_ids(
        const int* __restrict__ esrc, const int* __restrict__ edst,
        int* __restrict__ cursor, int* __restrict__ srcs) {
    const int grp = blockIdx.x & 7;
    const int blk = blockIdx.x >> 3;
    const int dlo = grp * (NN / 8), dhi = dlo + (NN / 8);
    for (int e = blk * 256 + threadIdx.x; e < NE; e += SCAT_BPG * 256) {
        int d = edst[e];
        if (d >= dlo && d < dhi) {
            int pos = atomicAdd(&cursor[d], 1);
            srcs[pos] = esrc[e];
        }
    }
}

// ---- fused node GEMMs via split-precision bf16 MFMA ----
// Block 256 thr = 4 waves; wave w: nodes nb0+16w..+15, all 192 outputs.
// LDS (shorts): xhi[64][40], xlo[64][40], W planes 6x[64][40] (pad 40 = 80B rows).
template <int DIN, bool RELU>
__global__ __launch_bounds__(256, 3) void k_gemm(
        const float* __restrict__ xin, const short* __restrict__ Ws,
        const float* __restrict__ bvec, const float* __restrict__ rb,
        float* __restrict__ xl, float* __restrict__ xr, float* __restrict__ acc) {
    constexpr int LROW = 40;
    __shared__ short lds[20480];            // 40 KB
    short* xhi = lds;                       // [64][40]
    short* xlo = lds + 2560;
    // W plane (m,p): lds + 5120 + (m*2+p)*2560, layout [64 c][40]

    const int tid = threadIdx.x;
    const int w = tid >> 6;
    const int lane = tid & 63;
    const int col = lane & 15;
    const int quad = lane >> 4;
    const int nb0 = blockIdx.x * 64;

    f32x4 d[3][4];
#pragma unroll
    for (int m = 0; m < 3; m++)
#pragma unroll
        for (int ct = 0; ct < 4; ct++) d[m][ct] = (f32x4){0.f, 0.f, 0.f, 0.f};

    for (int c0 = 0; c0 < DIN; c0 += 32) {
        if (c0) __syncthreads();
        // stage x: 64 rows x 8 float4 = 512 units, 2/thread; split to hi/lo
        for (int u = tid; u < 512; u += 256) {
            int row = u >> 3, kq = u & 7;
            int n = nb0 + row;
            float4 v = make_float4(0.f, 0.f, 0.f, 0.f);
            if (n < NN) {
                v = *(const float4*)&xin[(size_t)n * DIN + c0 + 4 * kq];
                if (RELU) {
                    v.x = fmaxf(v.x, 0.f); v.y = fmaxf(v.y, 0.f);
                    v.z = fmaxf(v.z, 0.f); v.w = fmaxf(v.w, 0.f);
                }
            }
            s4v h, l;
            short h0 = split_hi(v.x), l0 = split_lo(v.x, h0);
            short h1 = split_hi(v.y), l1 = split_lo(v.y, h1);
            short h2 = split_hi(v.z), l2 = split_lo(v.z, h2);
            short h3 = split_hi(v.w), l3 = split_lo(v.w, h3);
            h[0] = h0; h[1] = h1; h[2] = h2; h[3] = h3;
            l[0] = l0; l[1] = l1; l[2] = l2; l[3] = l3;
            *(s4v*)&xhi[row * LROW + 4 * kq] = h;
            *(s4v*)&xlo[row * LROW + 4 * kq] = l;
        }
        // stage W: 6 planes x 64 c x 4 x(8-short) = 1536 units, 6/thread
        for (int u = tid; u < 1536; u += 256) {
            int mp = u >> 8;
            int r = u & 255;
            int c = r >> 2, q = r & 3;
            s8v v = *(const s8v*)&Ws[((mp * HID + c) * DIN) + c0 + 8 * q];
            *(s8v*)&lds[5120 + mp * 2560 + c * LROW + 8 * q] = v;
        }
        __syncthreads();

        // A frags: lane holds x[node = 16w+col][k = 8*quad + j]
        bf16x8 a_h = __builtin_bit_cast(bf16x8,
            *(const s8v*)&xhi[(w * 16 + col) * LROW + quad * 8]);
        bf16x8 a_l = __builtin_bit_cast(bf16x8,
            *(const s8v*)&xlo[(w * 16 + col) * LROW + quad * 8]);

#pragma unroll
        for (int m = 0; m < 3; m++) {
#pragma unroll
            for (int ct = 0; ct < 4; ct++) {
                // B frag: lane holds W[c = 16ct+col][k = 8*quad + j]
                bf16x8 b_h = __builtin_bit_cast(bf16x8,
                    *(const s8v*)&lds[5120 + (m * 2 + 0) * 2560 + (ct * 16 + col) * LROW + quad * 8]);
                bf16x8 b_l = __builtin_bit_cast(bf16x8,
                    *(const s8v*)&lds[5120 + (m * 2 + 1) * 2560 + (ct * 16 + col) * LROW + quad * 8]);
                d[m][ct] = __builtin_amdgcn_mfma_f32_16x16x32_bf16(a_h, b_h, d[m][ct], 0, 0, 0);
                d[m][ct] = __builtin_amdgcn_mfma_f32_16x16x32_bf16(a_h, b_l, d[m][ct], 0, 0, 0);
                d[m][ct] = __builtin_amdgcn_mfma_f32_16x16x32_bf16(a_l, b_h, d[m][ct], 0, 0, 0);
            }
        }
    }

    // epilogue: D row = quad*4 + r (node), col = 16ct + col (channel)
#pragma unroll
    for (int r = 0; r < 4; r++) {
        int n = nb0 + w * 16 + quad * 4 + r;
        if (n >= NN) continue;
        size_t base = (size_t)n * HID;
#pragma unroll
        for (int ct = 0; ct < 4; ct++) {
            int c = ct * 16 + col;
            xl[base + c] = d[0][ct][r];
            xr[base + c] = d[1][ct][r];
            acc[base + c] = d[2][ct][r] + bvec[c] + rb[c];
        }
    }
}

// ---- fused per-dst attention: 8 edges x 8 channels per wave ----
__global__ __launch_bounds__(256) void k_attn_dst(
        const int* __restrict__ off, const int* __restrict__ srcs,
        const float* __restrict__ xl, const float* __restrict__ xr,
        const float* __restrict__ att, float* __restrict__ acc) {
    const int lane = threadIdx.x & 63;
    const int d = blockIdx.x * 4 + (threadIdx.x >> 6);
    if (d >= NN) return;
    const int e = lane >> 3;
    const int cg = lane & 7;

    const float4* xr4 = (const float4*)&xr[(size_t)d * HID + 8 * cg];
    float4 xra = xr4[0], xrb = xr4[1];
    const float4* at4 = (const float4*)&att[8 * cg];
    float4 ata = at4[0], atb = at4[1];

#define EDGE_LOGIT(S, XA, XB, T)                                               \
    {                                                                          \
        const float4* _x4 = (const float4*)&xl[(size_t)(S) * HID + 8 * cg];    \
        XA = _x4[0]; XB = _x4[1];                                              \
        float _ps;                                                             \
        float _v;                                                              \
        _v = XA.x + xra.x; _ps  = (fmaxf(_v,0.f) + NEG*fminf(_v,0.f)) * ata.x; \
        _v = XA.y + xra.y; _ps += (fmaxf(_v,0.f) + NEG*fminf(_v,0.f)) * ata.y; \
        _v = XA.z + xra.z; _ps += (fmaxf(_v,0.f) + NEG*fminf(_v,0.f)) * ata.z; \
        _v = XA.w + xra.w; _ps += (fmaxf(_v,0.f) + NEG*fminf(_v,0.f)) * ata.w; \
        _v = XB.x + xrb.x; _ps += (fmaxf(_v,0.f) + NEG*fminf(_v,0.f)) * atb.x; \
        _v = XB.y + xrb.y; _ps += (fmaxf(_v,0.f) + NEG*fminf(_v,0.f)) * atb.y; \
        _v = XB.z + xrb.z; _ps += (fmaxf(_v,0.f) + NEG*fminf(_v,0.f)) * atb.z; \
        _v = XB.w + xrb.w; _ps += (fmaxf(_v,0.f) + NEG*fminf(_v,0.f)) * atb.w; \
        _ps += __shfl_xor(_ps, 1, 64);                                         \
        _ps += __shfl_xor(_ps, 2, 64);                                         \
        _ps += __shfl_xor(_ps, 4, 64);                                         \
        T = _ps;                                                               \
    }

    float m, l;
    float4 oA, oB;
    {
        float4 xla, xlb; float t;
        EDGE_LOGIT(d, xla, xlb, t);
        m = t;
        bool own = (e == 0);
        l = own ? 1.f : 0.f;
        oA = own ? xla : make_float4(0.f, 0.f, 0.f, 0.f);
        oB = own ? xlb : make_float4(0.f, 0.f, 0.f, 0.f);
    }

    const int lo = off[d], deg = off[d + 1] - lo;
    for (int base = 0; base < deg; base += 8) {
        int nv = deg - base;
        int sv = 0;
        if (lane < 8) sv = srcs[lo + min(base + lane, deg - 1)];
        int s = __shfl(sv, e, 64);

        float4 xla, xlb; float t;
        EDGE_LOGIT(s, xla, xlb, t);
        if (e >= nv) t = -INFINITY;

        float cm = t;
        cm = fmaxf(cm, __shfl_xor(cm, 8, 64));
        cm = fmaxf(cm, __shfl_xor(cm, 16, 64));
        cm = fmaxf(cm, __shfl_xor(cm, 32, 64));
        float newm = fmaxf(m, cm);
        float corr = __expf(m - newm);
        float p = __expf(t - newm);
        m = newm;
        l = l * corr + p;
        oA.x = oA.x * corr + p * xla.x; oA.y = oA.y * corr + p * xla.y;
        oA.z = oA.z * corr + p * xla.z; oA.w = oA.w * corr + p * xla.w;
        oB.x = oB.x * corr + p * xlb.x; oB.y = oB.y * corr + p * xlb.y;
        oB.z = oB.z * corr + p * xlb.z; oB.w = oB.w * corr + p * xlb.w;
    }
#undef EDGE_LOGIT

#pragma unroll
    for (int w = 8; w <= 32; w <<= 1) {
        l    += __shfl_xor(l, w, 64);
        oA.x += __shfl_xor(oA.x, w, 64); oA.y += __shfl_xor(oA.y, w, 64);
        oA.z += __shfl_xor(oA.z, w, 64); oA.w += __shfl_xor(oA.w, w, 64);
        oB.x += __shfl_xor(oB.x, w, 64); oB.y += __shfl_xor(oB.y, w, 64);
        oB.z += __shfl_xor(oB.z, w, 64); oB.w += __shfl_xor(oB.w, w, 64);
    }

    if (e == 0) {
        float inv = 1.f / l;
        float4* a4 = (float4*)&acc[(size_t)d * HID + 8 * cg];
        float4 c0 = a4[0], c1 = a4[1];
        c0.x += oA.x * inv; c0.y += oA.y * inv;
        c0.z += oA.z * inv; c0.w += oA.w * inv;
        c1.x += oB.x * inv; c1.y += oB.y * inv;
        c1.z += oB.z * inv; c1.w += oB.w * inv;
        a4[0] = c0; a4[1] = c1;
    }
}

// ---- fused mean-pool + head: one block (512 thr) per graph ----
__global__ __launch_bounds__(512) void k_pool_final(
        const float* __restrict__ acc,
        const int* __restrict__ startg, const int* __restrict__ endg,
        const float* __restrict__ Wf, const float* __restrict__ bf_,
        float* __restrict__ out) {
    __shared__ float red[8][HID];
    const int g = blockIdx.x;
    const int c = threadIdx.x & 63;
    const int j = threadIdx.x >> 6;
    const int s = startg[g], epos = endg[g];

    float sum = 0.f;
    for (int n = s + j; n < epos; n += 8)
        sum += acc[(size_t)n * HID + c];
    red[j][c] = sum;
    __syncthreads();

    if (threadIdx.x < HID) {
        float tot = 0.f;
#pragma unroll
        for (int w = 0; w < 8; w++) tot += red[w][c];
        float cntf = (float)(epos - s);
        float v = tot / fmaxf(cntf, 1.f) * Wf[c];
#pragma unroll
        for (int o = 32; o; o >>= 1) v += __shfl_xor(v, o, 64);
        if (c == 0) out[g] = v + bf_[0];
    }
}

extern "C" void kernel_launch(void* const* d_in, const int* in_sizes, int n_in,
                              void* d_out, int out_size, void* d_ws, size_t ws_size,
                              hipStream_t stream) {
    const float* x   = (const float*)d_in[0];
    const int* eidx  = (const int*)d_in[1];
    const int* batch = (const int*)d_in[2];
    const int* esrc = eidx;
    const int* edst = eidx + NE;
    const float* Wf  = (const float*)d_in[21];
    const float* bfb = (const float*)d_in[22];

    float* wsf = (float*)d_ws;
    const size_t NN64 = (size_t)NN * HID;
    float* xl     = wsf;
    float* xr     = xl + NN64;
    float* acc0   = xr + NN64;
    float* acc1   = acc0 + NN64;
    short* Ws0    = (short*)(acc1 + NN64);          // 2*3*64*128 shorts
    short* Ws1    = Ws0 + 2 * 3 * HID * DIN0;       // 2*3*64*64
    short* Ws2    = Ws1 + 2 * 3 * HID * HID;
    int*   ccnt   = (int*)(Ws2 + 2 * 3 * HID * HID);
    int*   startg = ccnt + NN;
    int*   endg   = startg + NG;
    int*   off    = endg + NG;
    int*   cursor = off + NN + 1;
    int*   part   = cursor + NN;
    int*   partSc = part + SNB;
    int*   cnt8   = partSc + SNB;          // 8*NN
    int*   srcs   = cnt8 + 8 * NN;

    // setup: merged weight split (+zero startg/endg), bounds (+zero cnt8)
    k_wt_all<<<(3 * HID * DIN0 + 2 * 3 * HID * HID + 255) / 256, 256, 0, stream>>>(
        (const float*)d_in[3], (const float*)d_in[4], (const float*)d_in[7],
        (const float*)d_in[9], (const float*)d_in[10], (const float*)d_in[13],
        (const float*)d_in[15], (const float*)d_in[16], (const float*)d_in[19],
        Ws0, Ws1, Ws2, startg, endg);
    k_bounds<<<(NN + 255) / 256, 256, 0, stream>>>(batch, startg, endg, cnt8);

    // CSR build
    k_hist8<<<512, 256, 0, stream>>>(edst, cnt8);
    k_hist_red<<<(NN + 255) / 256, 256, 0, stream>>>(cnt8, ccnt);
    k_scan_part<<<SNB, 256, 0, stream>>>(ccnt, part);
    k_scan_small<<<1, 64, 0, stream>>>(part, partSc);
    k_scan_emit<<<SNB, 256, 0, stream>>>(ccnt, partSc, off, cursor);
    k_scatter_ids<<<8 * SCAT_BPG, 256, 0, stream>>>(esrc, edst, cursor, srcs);

    const short* Wss[3] = {Ws0, Ws1, Ws2};
    float* accs[4] = {acc0, acc0, acc1, acc0};  // out of layer L = accs[L+1]
    const int gemm_grid = (NN + 63) / 64;
    for (int L = 0; L < 3; L++) {
        const float* att = (const float*)d_in[3 + L * 6 + 2];
        const float* b   = (const float*)d_in[3 + L * 6 + 3];
        const float* Rb  = (const float*)d_in[3 + L * 6 + 5];
        float* accOut = accs[L + 1];

        if (L == 0)
            k_gemm<DIN0, false><<<gemm_grid, 256, 0, stream>>>(
                x, Wss[0], b, Rb, xl, xr, accOut);
        else
            k_gemm<HID, true><<<gemm_grid, 256, 0, stream>>>(
                accs[L], Wss[L], b, Rb, xl, xr, accOut);

        k_attn_dst<<<(NN + 3) / 4, 256, 0, stream>>>(off, srcs, xl, xr, att, accOut);
    }

    k_pool_final<<<NG, 512, 0, stream>>>(accs[3], startg, endg, Wf, bfb, (float*)d_out);
}

// Round 18
// 413.193 us; speedup vs baseline: 1.2846x; 1.0006x over previous
//
#include <hip/hip_runtime.h>

// GATv2 3-layer + mean-pool + linear head, MI355X.
// R17: xl stored as fp16 (attn's only consumer) — halves the 270MB/layer
// gather traffic in k_attn_dst (one b128/lane instead of two) and the gemm
// xl-write. fp16 (not bf16: 10 mantissa bits) keeps end-to-end error ~2e-3
// vs 1.2e-2 threshold. gemm = split-precision bf16 MFMA (R16, verified).

#define NN 50000
#define NE 1000000
#define HID 64
#define DIN0 128
#define NG 256
#define NEG 0.2f

#define SCHUNK 1024
#define SNB ((NN + SCHUNK - 1) / SCHUNK)   // 49 blocks

typedef float f32x4 __attribute__((ext_vector_type(4)));
typedef short s8v __attribute__((ext_vector_type(8)));
typedef short s4v __attribute__((ext_vector_type(4)));
typedef __bf16 bf16x8 __attribute__((ext_vector_type(8)));
typedef _Float16 h8v __attribute__((ext_vector_type(8)));

__device__ __forceinline__ unsigned short f2bf(float f) {
    unsigned u = __float_as_uint(f);
    u = u + 0x7fffu + ((u >> 16) & 1u);   // RNE
    return (unsigned short)(u >> 16);
}
__device__ __forceinline__ float bf2f(unsigned short v) {
    return __uint_as_float(((unsigned)v) << 16);
}
__device__ __forceinline__ short split_hi(float x) {
    return (short)f2bf(x);
}
__device__ __forceinline__ short split_lo(float x, short hi) {
    return (short)f2bf(x - bf2f((unsigned short)hi));
}

// ---- merged weight pre-split (all 3 layers) + zero startg/endg ----
__global__ __launch_bounds__(256) void k_wt_all(
        const float* __restrict__ Wl0, const float* __restrict__ Wr0, const float* __restrict__ Rw0,
        const float* __restrict__ Wl1, const float* __restrict__ Wr1, const float* __restrict__ Rw1,
        const float* __restrict__ Wl2, const float* __restrict__ Wr2, const float* __restrict__ Rw2,
        short* __restrict__ Ws0, short* __restrict__ Ws1, short* __restrict__ Ws2,
        int* __restrict__ startg, int* __restrict__ endg) {
    int i = blockIdx.x * 256 + threadIdx.x;
    if (i < 2 * NG) {
        if (i < NG) startg[i] = 0; else endg[i - NG] = 0;
    }
    const int L0N = 3 * HID * DIN0;
    const int L1N = 3 * HID * HID;
    if (i >= L0N + 2 * L1N) return;
    const float* Wm; short* Ws; int din, local;
    if (i < L0N) {
        local = i; din = DIN0; Ws = Ws0;
        int m = local / (DIN0 * HID);
        Wm = (m == 0) ? Wl0 : (m == 1) ? Wr0 : Rw0;
    } else if (i < L0N + L1N) {
        local = i - L0N; din = HID; Ws = Ws1;
        int m = local / (HID * HID);
        Wm = (m == 0) ? Wl1 : (m == 1) ? Wr1 : Rw1;
    } else {
        local = i - L0N - L1N; din = HID; Ws = Ws2;
        int m = local / (HID * HID);
        Wm = (m == 0) ? Wl2 : (m == 1) ? Wr2 : Rw2;
    }
    int m = local / (din * HID);
    int r = local - m * (din * HID);
    int c = r / din, k = r - c * din;
    float w = Wm[c * din + k];
    short hi = split_hi(w);
    short lo = split_lo(w, hi);
    Ws[(((m * 2 + 0) * HID + c) * din) + k] = hi;
    Ws[(((m * 2 + 1) * HID + c) * din) + k] = lo;
}

// ---- graph bounds + zero hist slices ----
__global__ void k_bounds(const int* __restrict__ batch,
                         int* __restrict__ startg, int* __restrict__ endg,
                         int* __restrict__ cnt8) {
    int i = blockIdx.x * 256 + threadIdx.x;
    if (i >= NN) return;
#pragma unroll
    for (int g = 0; g < 8; g++) cnt8[g * NN + i] = 0;
    int g = batch[i];
    if (i == 0 || batch[i - 1] != g) startg[g] = i;
    if (i == NN - 1 || batch[i + 1] != g) endg[g] = i + 1;
}

__global__ __launch_bounds__(256) void k_hist8(const int* __restrict__ edst,
                                               int* __restrict__ cnt8) {
    int* mycnt = cnt8 + (blockIdx.x & 7) * NN;
    for (int e = blockIdx.x * 256 + threadIdx.x; e < NE; e += 512 * 256)
        atomicAdd(&mycnt[edst[e]], 1);
}

__global__ void k_hist_red(const int* __restrict__ cnt8, int* __restrict__ cnt) {
    int i = blockIdx.x * 256 + threadIdx.x;
    if (i >= NN) return;
    int s = 0;
#pragma unroll
    for (int g = 0; g < 8; g++) s += cnt8[g * NN + i];
    cnt[i] = s;
}

__global__ __launch_bounds__(256) void k_scan_part(const int* __restrict__ cnt,
                                                   int* __restrict__ part) {
    __shared__ int ws[4];
    int b = blockIdx.x, t = threadIdx.x;
    int i0 = b * SCHUNK + t * 4;
    int s = 0;
#pragma unroll
    for (int j = 0; j < 4; j++) {
        int i = i0 + j;
        if (i < NN) s += cnt[i];
    }
#pragma unroll
    for (int o = 32; o; o >>= 1) s += __shfl_xor(s, o, 64);
    if ((t & 63) == 0) ws[t >> 6] = s;
    __syncthreads();
    if (t == 0) part[b] = ws[0] + ws[1] + ws[2] + ws[3];
}

__global__ void k_scan_small(const int* __restrict__ part, int* __restrict__ partScan) {
    __shared__ int sh[SNB];
    int t = threadIdx.x;
    if (t < SNB) sh[t] = part[t];
    __syncthreads();
    if (t < SNB) {
        int s = 0;
        for (int i = 0; i < t; i++) s += sh[i];
        partScan[t] = s;
    }
}

__global__ __launch_bounds__(256) void k_scan_emit(const int* __restrict__ cnt,
                                                   const int* __restrict__ partScan,
                                                   int* __restrict__ off,
                                                   int* __restrict__ cursor) {
    __shared__ int tsum[256];
    int b = blockIdx.x, t = threadIdx.x;
    int i0 = b * SCHUNK + t * 4;
    int e[4], p[4];
    int s = 0;
#pragma unroll
    for (int j = 0; j < 4; j++) {
        int i = i0 + j;
        e[j] = (i < NN) ? cnt[i] : 0;
        p[j] = s;
        s += e[j];
    }
    tsum[t] = s;
    __syncthreads();
    for (int d = 1; d < 256; d <<= 1) {
        int v = (t >= d) ? tsum[t - d] : 0;
        __syncthreads();
        tsum[t] += v;
        __syncthreads();
    }
    int base = partScan[b] + ((t == 0) ? 0 : tsum[t - 1]);
#pragma unroll
    for (int j = 0; j < 4; j++) {
        int i = i0 + j;
        if (i < NN) {
            int v = base + p[j];
            off[i] = v; cursor[i] = v;
            if (i == NN - 1) off[NN] = v + e[j];
        }
    }
}

#define SCAT_BPG 96
__global__ __launch_bounds__(256) void k_scatter_ids(
        const int* __restrict__ esrc, const int* __restrict__ edst,
        int* __restrict__ cursor, int* __restrict__ srcs) {
    const int grp = blockIdx.x & 7;
    const int blk = blockIdx.x >> 3;
    const int dlo = grp * (NN / 8), dhi = dlo + (NN / 8);
    for (int e = blk * 256 + threadIdx.x; e < NE; e += SCAT_BPG * 256) {
        int d = edst[e];
        if (d >= dlo && d < dhi) {
            int pos = atomicAdd(&cursor[d], 1);
            srcs[pos] = esrc[e];
        }
    }
}

// ---- fused node GEMMs via split-precision bf16 MFMA; xl output as fp16 ----
template <int DIN, bool RELU>
__global__ __launch_bounds__(256, 3) void k_gemm(
        const float* __restrict__ xin, const short* __restrict__ Ws,
        const float* __restrict__ bvec, const float* __restrict__ rb,
        _Float16* __restrict__ xl16, float* __restrict__ xr, float* __restrict__ acc) {
    constexpr int LROW = 40;
    __shared__ short lds[20480];            // 40 KB
    short* xhi = lds;
    short* xlo = lds + 2560;

    const int tid = threadIdx.x;
    const int w = tid >> 6;
    const int lane = tid & 63;
    const int col = lane & 15;
    const int quad = lane >> 4;
    const int nb0 = blockIdx.x * 64;

    f32x4 d[3][4];
#pragma unroll
    for (int m = 0; m < 3; m++)
#pragma unroll
        for (int ct = 0; ct < 4; ct++) d[m][ct] = (f32x4){0.f, 0.f, 0.f, 0.f};

    for (int c0 = 0; c0 < DIN; c0 += 32) {
        if (c0) __syncthreads();
        for (int u = tid; u < 512; u += 256) {
            int row = u >> 3, kq = u & 7;
            int n = nb0 + row;
            float4 v = make_float4(0.f, 0.f, 0.f, 0.f);
            if (n < NN) {
                v = *(const float4*)&xin[(size_t)n * DIN + c0 + 4 * kq];
                if (RELU) {
                    v.x = fmaxf(v.x, 0.f); v.y = fmaxf(v.y, 0.f);
                    v.z = fmaxf(v.z, 0.f); v.w = fmaxf(v.w, 0.f);
                }
            }
            s4v h, l;
            short h0 = split_hi(v.x), l0 = split_lo(v.x, h0);
            short h1 = split_hi(v.y), l1 = split_lo(v.y, h1);
            short h2 = split_hi(v.z), l2 = split_lo(v.z, h2);
            short h3 = split_hi(v.w), l3 = split_lo(v.w, h3);
            h[0] = h0; h[1] = h1; h[2] = h2; h[3] = h3;
            l[0] = l0; l[1] = l1; l[2] = l2; l[3] = l3;
            *(s4v*)&xhi[row * LROW + 4 * kq] = h;
            *(s4v*)&xlo[row * LROW + 4 * kq] = l;
        }
        for (int u = tid; u < 1536; u += 256) {
            int mp = u >> 8;
            int r = u & 255;
            int c = r >> 2, q = r & 3;
            s8v v = *(const s8v*)&Ws[((mp * HID + c) * DIN) + c0 + 8 * q];
            *(s8v*)&lds[5120 + mp * 2560 + c * LROW + 8 * q] = v;
        }
        __syncthreads();

        bf16x8 a_h = __builtin_bit_cast(bf16x8,
            *(const s8v*)&xhi[(w * 16 + col) * LROW + quad * 8]);
        bf16x8 a_l = __builtin_bit_cast(bf16x8,
            *(const s8v*)&xlo[(w * 16 + col) * LROW + quad * 8]);

#pragma unroll
        for (int m = 0; m < 3; m++) {
#pragma unroll
            for (int ct = 0; ct < 4; ct++) {
                bf16x8 b_h = __builtin_bit_cast(bf16x8,
                    *(const s8v*)&lds[5120 + (m * 2 + 0) * 2560 + (ct * 16 + col) * LROW + quad * 8]);
                bf16x8 b_l = __builtin_bit_cast(bf16x8,
                    *(const s8v*)&lds[5120 + (m * 2 + 1) * 2560 + (ct * 16 + col) * LROW + quad * 8]);
                d[m][ct] = __builtin_amdgcn_mfma_f32_16x16x32_bf16(a_h, b_h, d[m][ct], 0, 0, 0);
                d[m][ct] = __builtin_amdgcn_mfma_f32_16x16x32_bf16(a_h, b_l, d[m][ct], 0, 0, 0);
                d[m][ct] = __builtin_amdgcn_mfma_f32_16x16x32_bf16(a_l, b_h, d[m][ct], 0, 0, 0);
            }
        }
    }

#pragma unroll
    for (int r = 0; r < 4; r++) {
        int n = nb0 + w * 16 + quad * 4 + r;
        if (n >= NN) continue;
        size_t base = (size_t)n * HID;
#pragma unroll
        for (int ct = 0; ct < 4; ct++) {
            int c = ct * 16 + col;
            xl16[base + c] = (_Float16)d[0][ct][r];
            xr[base + c] = d[1][ct][r];
            acc[base + c] = d[2][ct][r] + bvec[c] + rb[c];
        }
    }
}

// ---- fused per-dst attention: 8 edges x 8 channels per wave, fp16 xl ----
__global__ __launch_bounds__(256) void k_attn_dst(
        const int* __restrict__ off, const int* __restrict__ srcs,
        const _Float16* __restrict__ xl16, const float* __restrict__ xr,
        const float* __restrict__ att, float* __restrict__ acc) {
    const int lane = threadIdx.x & 63;
    const int d = blockIdx.x * 4 + (threadIdx.x >> 6);
    if (d >= NN) return;
    const int e = lane >> 3;
    const int cg = lane & 7;

    const float4* xr4 = (const float4*)&xr[(size_t)d * HID + 8 * cg];
    float4 xra = xr4[0], xrb = xr4[1];
    const float4* at4 = (const float4*)&att[8 * cg];
    float4 ata = at4[0], atb = at4[1];

#define EDGE_LOGIT(S, XA, XB, T)                                               \
    {                                                                          \
        h8v _hv = *(const h8v*)&xl16[(size_t)(S) * HID + 8 * cg];              \
        XA.x = (float)_hv[0]; XA.y = (float)_hv[1];                            \
        XA.z = (float)_hv[2]; XA.w = (float)_hv[3];                            \
        XB.x = (float)_hv[4]; XB.y = (float)_hv[5];                            \
        XB.z = (float)_hv[6]; XB.w = (float)_hv[7];                            \
        float _ps;                                                             \
        float _v;                                                              \
        _v = XA.x + xra.x; _ps  = (fmaxf(_v,0.f) + NEG*fminf(_v,0.f)) * ata.x; \
        _v = XA.y + xra.y; _ps += (fmaxf(_v,0.f) + NEG*fminf(_v,0.f)) * ata.y; \
        _v = XA.z + xra.z; _ps += (fmaxf(_v,0.f) + NEG*fminf(_v,0.f)) * ata.z; \
        _v = XA.w + xra.w; _ps += (fmaxf(_v,0.f) + NEG*fminf(_v,0.f)) * ata.w; \
        _v = XB.x + xrb.x; _ps += (fmaxf(_v,0.f) + NEG*fminf(_v,0.f)) * atb.x; \
        _v = XB.y + xrb.y; _ps += (fmaxf(_v,0.f) + NEG*fminf(_v,0.f)) * atb.y; \
        _v = XB.z + xrb.z; _ps += (fmaxf(_v,0.f) + NEG*fminf(_v,0.f)) * atb.z; \
        _v = XB.w + xrb.w; _ps += (fmaxf(_v,0.f) + NEG*fminf(_v,0.f)) * atb.w; \
        _ps += __shfl_xor(_ps, 1, 64);                                         \
        _ps += __shfl_xor(_ps, 2, 64);                                         \
        _ps += __shfl_xor(_ps, 4, 64);                                         \
        T = _ps;                                                               \
    }

    float m, l;
    float4 oA, oB;
    {
        float4 xla, xlb; float t;
        EDGE_LOGIT(d, xla, xlb, t);
        m = t;
        bool own = (e == 0);
        l = own ? 1.f : 0.f;
        oA = own ? xla : make_float4(0.f, 0.f, 0.f, 0.f);
        oB = own ? xlb : make_float4(0.f, 0.f, 0.f, 0.f);
    }

    const int lo = off[d], deg = off[d + 1] - lo;
    for (int base = 0; base < deg; base += 8) {
        int nv = deg - base;
        int sv = 0;
        if (lane < 8) sv = srcs[lo + min(base + lane, deg - 1)];
        int s = __shfl(sv, e, 64);

        float4 xla, xlb; float t;
        EDGE_LOGIT(s, xla, xlb, t);
        if (e >= nv) t = -INFINITY;

        float cm = t;
        cm = fmaxf(cm, __shfl_xor(cm, 8, 64));
        cm = fmaxf(cm, __shfl_xor(cm, 16, 64));
        cm = fmaxf(cm, __shfl_xor(cm, 32, 64));
        float newm = fmaxf(m, cm);
        float corr = __expf(m - newm);
        float p = __expf(t - newm);
        m = newm;
        l = l * corr + p;
        oA.x = oA.x * corr + p * xla.x; oA.y = oA.y * corr + p * xla.y;
        oA.z = oA.z * corr + p * xla.z; oA.w = oA.w * corr + p * xla.w;
        oB.x = oB.x * corr + p * xlb.x; oB.y = oB.y * corr + p * xlb.y;
        oB.z = oB.z * corr + p * xlb.z; oB.w = oB.w * corr + p * xlb.w;
    }
#undef EDGE_LOGIT

#pragma unroll
    for (int w = 8; w <= 32; w <<= 1) {
        l    += __shfl_xor(l, w, 64);
        oA.x += __shfl_xor(oA.x, w, 64); oA.y += __shfl_xor(oA.y, w, 64);
        oA.z += __shfl_xor(oA.z, w, 64); oA.w += __shfl_xor(oA.w, w, 64);
        oB.x += __shfl_xor(oB.x, w, 64); oB.y += __shfl_xor(oB.y, w, 64);
        oB.z += __shfl_xor(oB.z, w, 64); oB.w += __shfl_xor(oB.w, w, 64);
    }

    if (e == 0) {
        float inv = 1.f / l;
        float4* a4 = (float4*)&acc[(size_t)d * HID + 8 * cg];
        float4 c0 = a4[0], c1 = a4[1];
        c0.x += oA.x * inv; c0.y += oA.y * inv;
        c0.z += oA.z * inv; c0.w += oA.w * inv;
        c1.x += oB.x * inv; c1.y += oB.y * inv;
        c1.z += oB.z * inv; c1.w += oB.w * inv;
        a4[0] = c0; a4[1] = c1;
    }
}

// ---- fused mean-pool + head ----
__global__ __launch_bounds__(512) void k_pool_final(
        const float* __restrict__ acc,
        const int* __restrict__ startg, const int* __restrict__ endg,
        const float* __restrict__ Wf, const float* __restrict__ bf_,
        float* __restrict__ out) {
    __shared__ float red[8][HID];
    const int g = blockIdx.x;
    const int c = threadIdx.x & 63;
    const int j = threadIdx.x >> 6;
    const int s = startg[g], epos = endg[g];

    float sum = 0.f;
    for (int n = s + j; n < epos; n += 8)
        sum += acc[(size_t)n * HID + c];
    red[j][c] = sum;
    __syncthreads();

    if (threadIdx.x < HID) {
        float tot = 0.f;
#pragma unroll
        for (int w = 0; w < 8; w++) tot += red[w][c];
        float cntf = (float)(epos - s);
        float v = tot / fmaxf(cntf, 1.f) * Wf[c];
#pragma unroll
        for (int o = 32; o; o >>= 1) v += __shfl_xor(v, o, 64);
        if (c == 0) out[g] = v + bf_[0];
    }
}

extern "C" void kernel_launch(void* const* d_in, const int* in_sizes, int n_in,
                              void* d_out, int out_size, void* d_ws, size_t ws_size,
                              hipStream_t stream) {
    const float* x   = (const float*)d_in[0];
    const int* eidx  = (const int*)d_in[1];
    const int* batch = (const int*)d_in[2];
    const int* esrc = eidx;
    const int* edst = eidx + NE;
    const float* Wf  = (const float*)d_in[21];
    const float* bfb = (const float*)d_in[22];

    float* wsf = (float*)d_ws;
    const size_t NN64 = (size_t)NN * HID;
    _Float16* xl16 = (_Float16*)wsf;                // NN64 halfs (fits in NN64/2 floats)
    float* xr     = wsf + NN64;
    float* acc0   = xr + NN64;
    float* acc1   = acc0 + NN64;
    short* Ws0    = (short*)(acc1 + NN64);
    short* Ws1    = Ws0 + 2 * 3 * HID * DIN0;
    short* Ws2    = Ws1 + 2 * 3 * HID * HID;
    int*   ccnt   = (int*)(Ws2 + 2 * 3 * HID * HID);
    int*   startg = ccnt + NN;
    int*   endg   = startg + NG;
    int*   off    = endg + NG;
    int*   cursor = off + NN + 1;
    int*   part   = cursor + NN;
    int*   partSc = part + SNB;
    int*   cnt8   = partSc + SNB;
    int*   srcs   = cnt8 + 8 * NN;

    k_wt_all<<<(3 * HID * DIN0 + 2 * 3 * HID * HID + 255) / 256, 256, 0, stream>>>(
        (const float*)d_in[3], (const float*)d_in[4], (const float*)d_in[7],
        (const float*)d_in[9], (const float*)d_in[10], (const float*)d_in[13],
        (const float*)d_in[15], (const float*)d_in[16], (const float*)d_in[19],
        Ws0, Ws1, Ws2, startg, endg);
    k_bounds<<<(NN + 255) / 256, 256, 0, stream>>>(batch, startg, endg, cnt8);

    k_hist8<<<512, 256, 0, stream>>>(edst, cnt8);
    k_hist_red<<<(NN + 255) / 256, 256, 0, stream>>>(cnt8, ccnt);
    k_scan_part<<<SNB, 256, 0, stream>>>(ccnt, part);
    k_scan_small<<<1, 64, 0, stream>>>(part, partSc);
    k_scan_emit<<<SNB, 256, 0, stream>>>(ccnt, partSc, off, cursor);
    k_scatter_ids<<<8 * SCAT_BPG, 256, 0, stream>>>(esrc, edst, cursor, srcs);

    const short* Wss[3] = {Ws0, Ws1, Ws2};
    float* accs[4] = {acc0, acc0, acc1, acc0};  // out of layer L = accs[L+1]
    const int gemm_grid = (NN + 63) / 64;
    for (int L = 0; L < 3; L++) {
        const float* att = (const float*)d_in[3 + L * 6 + 2];
        const float* b   = (const float*)d_in[3 + L * 6 + 3];
        const float* Rb  = (const float*)d_in[3 + L * 6 + 5];
        float* accOut = accs[L + 1];

        if (L == 0)
            k_gemm<DIN0, false><<<gemm_grid, 256, 0, stream>>>(
                x, Wss[0], b, Rb, xl16, xr, accOut);
        else
            k_gemm<HID, true><<<gemm_grid, 256, 0, stream>>>(
                accs[L], Wss[L], b, Rb, xl16, xr, accOut);

        k_attn_dst<<<(NN + 3) / 4, 256, 0, stream>>>(off, srcs, xl16, xr, att, accOut);
    }

    k_pool_final<<<NG, 512, 0, stream>>>(accs[3], startg, endg, Wf, bfb, (float*)d_out);
}

// Round 19
// 408.235 us; speedup vs baseline: 1.3002x; 1.0121x over previous
//
#include <hip/hip_runtime.h>

// GATv2 3-layer + mean-pool + linear head, MI355X.
// R18: (1) srcs CSR stored as u16 (ids < 65536) — halves scatter payload and
//      its partial-line WRITE amplification (39MB observed for 4MB payload).
//      (2) attn processes 16 edges/iter (2 per e-slot) — halves the serial
//      softmax-update chain that R18 showed to be the real attn limiter
//      (fp16 gather-byte halving was neutral -> latency-bound, not BW-bound).

#define NN 50000
#define NE 1000000
#define HID 64
#define DIN0 128
#define NG 256
#define NEG 0.2f

#define SCHUNK 1024
#define SNB ((NN + SCHUNK - 1) / SCHUNK)   // 49 blocks

typedef float f32x4 __attribute__((ext_vector_type(4)));
typedef short s8v __attribute__((ext_vector_type(8)));
typedef short s4v __attribute__((ext_vector_type(4)));
typedef __bf16 bf16x8 __attribute__((ext_vector_type(8)));
typedef _Float16 h8v __attribute__((ext_vector_type(8)));
typedef unsigned short u16;

__device__ __forceinline__ unsigned short f2bf(float f) {
    unsigned u = __float_as_uint(f);
    u = u + 0x7fffu + ((u >> 16) & 1u);   // RNE
    return (unsigned short)(u >> 16);
}
__device__ __forceinline__ float bf2f(unsigned short v) {
    return __uint_as_float(((unsigned)v) << 16);
}
__device__ __forceinline__ short split_hi(float x) {
    return (short)f2bf(x);
}
__device__ __forceinline__ short split_lo(float x, short hi) {
    return (short)f2bf(x - bf2f((unsigned short)hi));
}

// ---- merged weight pre-split (all 3 layers) + zero startg/endg ----
__global__ __launch_bounds__(256) void k_wt_all(
        const float* __restrict__ Wl0, const float* __restrict__ Wr0, const float* __restrict__ Rw0,
        const float* __restrict__ Wl1, const float* __restrict__ Wr1, const float* __restrict__ Rw1,
        const float* __restrict__ Wl2, const float* __restrict__ Wr2, const float* __restrict__ Rw2,
        short* __restrict__ Ws0, short* __restrict__ Ws1, short* __restrict__ Ws2,
        int* __restrict__ startg, int* __restrict__ endg) {
    int i = blockIdx.x * 256 + threadIdx.x;
    if (i < 2 * NG) {
        if (i < NG) startg[i] = 0; else endg[i - NG] = 0;
    }
    const int L0N = 3 * HID * DIN0;
    const int L1N = 3 * HID * HID;
    if (i >= L0N + 2 * L1N) return;
    const float* Wm; short* Ws; int din, local;
    if (i < L0N) {
        local = i; din = DIN0; Ws = Ws0;
        int m = local / (DIN0 * HID);
        Wm = (m == 0) ? Wl0 : (m == 1) ? Wr0 : Rw0;
    } else if (i < L0N + L1N) {
        local = i - L0N; din = HID; Ws = Ws1;
        int m = local / (HID * HID);
        Wm = (m == 0) ? Wl1 : (m == 1) ? Wr1 : Rw1;
    } else {
        local = i - L0N - L1N; din = HID; Ws = Ws2;
        int m = local / (HID * HID);
        Wm = (m == 0) ? Wl2 : (m == 1) ? Wr2 : Rw2;
    }
    int m = local / (din * HID);
    int r = local - m * (din * HID);
    int c = r / din, k = r - c * din;
    float w = Wm[c * din + k];
    short hi = split_hi(w);
    short lo = split_lo(w, hi);
    Ws[(((m * 2 + 0) * HID + c) * din) + k] = hi;
    Ws[(((m * 2 + 1) * HID + c) * din) + k] = lo;
}

// ---- graph bounds + zero hist slices ----
__global__ void k_bounds(const int* __restrict__ batch,
                         int* __restrict__ startg, int* __restrict__ endg,
                         int* __restrict__ cnt8) {
    int i = blockIdx.x * 256 + threadIdx.x;
    if (i >= NN) return;
#pragma unroll
    for (int g = 0; g < 8; g++) cnt8[g * NN + i] = 0;
    int g = batch[i];
    if (i == 0 || batch[i - 1] != g) startg[g] = i;
    if (i == NN - 1 || batch[i + 1] != g) endg[g] = i + 1;
}

__global__ __launch_bounds__(256) void k_hist8(const int* __restrict__ edst,
                                               int* __restrict__ cnt8) {
    int* mycnt = cnt8 + (blockIdx.x & 7) * NN;
    for (int e = blockIdx.x * 256 + threadIdx.x; e < NE; e += 512 * 256)
        atomicAdd(&mycnt[edst[e]], 1);
}

__global__ void k_hist_red(const int* __restrict__ cnt8, int* __restrict__ cnt) {
    int i = blockIdx.x * 256 + threadIdx.x;
    if (i >= NN) return;
    int s = 0;
#pragma unroll
    for (int g = 0; g < 8; g++) s += cnt8[g * NN + i];
    cnt[i] = s;
}

__global__ __launch_bounds__(256) void k_scan_part(const int* __restrict__ cnt,
                                                   int* __restrict__ part) {
    __shared__ int ws[4];
    int b = blockIdx.x, t = threadIdx.x;
    int i0 = b * SCHUNK + t * 4;
    int s = 0;
#pragma unroll
    for (int j = 0; j < 4; j++) {
        int i = i0 + j;
        if (i < NN) s += cnt[i];
    }
#pragma unroll
    for (int o = 32; o; o >>= 1) s += __shfl_xor(s, o, 64);
    if ((t & 63) == 0) ws[t >> 6] = s;
    __syncthreads();
    if (t == 0) part[b] = ws[0] + ws[1] + ws[2] + ws[3];
}

__global__ void k_scan_small(const int* __restrict__ part, int* __restrict__ partScan) {
    __shared__ int sh[SNB];
    int t = threadIdx.x;
    if (t < SNB) sh[t] = part[t];
    __syncthreads();
    if (t < SNB) {
        int s = 0;
        for (int i = 0; i < t; i++) s += sh[i];
        partScan[t] = s;
    }
}

__global__ __launch_bounds__(256) void k_scan_emit(const int* __restrict__ cnt,
                                                   const int* __restrict__ partScan,
                                                   int* __restrict__ off,
                                                   int* __restrict__ cursor) {
    __shared__ int tsum[256];
    int b = blockIdx.x, t = threadIdx.x;
    int i0 = b * SCHUNK + t * 4;
    int e[4], p[4];
    int s = 0;
#pragma unroll
    for (int j = 0; j < 4; j++) {
        int i = i0 + j;
        e[j] = (i < NN) ? cnt[i] : 0;
        p[j] = s;
        s += e[j];
    }
    tsum[t] = s;
    __syncthreads();
    for (int d = 1; d < 256; d <<= 1) {
        int v = (t >= d) ? tsum[t - d] : 0;
        __syncthreads();
        tsum[t] += v;
        __syncthreads();
    }
    int base = partScan[b] + ((t == 0) ? 0 : tsum[t - 1]);
#pragma unroll
    for (int j = 0; j < 4; j++) {
        int i = i0 + j;
        if (i < NN) {
            int v = base + p[j];
            off[i] = v; cursor[i] = v;
            if (i == NN - 1) off[NN] = v + e[j];
        }
    }
}

#define SCAT_BPG 96
__global__ __launch_bounds__(256) void k_scatter_ids(
        const int* __restrict__ esrc, const int* __restrict__ edst,
        int* __restrict__ cursor, u16* __restrict__ srcs) {
    const int grp = blockIdx.x & 7;
    const int blk = blockIdx.x >> 3;
    const int dlo = grp * (NN / 8), dhi = dlo + (NN / 8);
    for (int e = blk * 256 + threadIdx.x; e < NE; e += SCAT_BPG * 256) {
        int d = edst[e];
        if (d >= dlo && d < dhi) {
            int pos = atomicAdd(&cursor[d], 1);
            srcs[pos] = (u16)esrc[e];
        }
    }
}

// ---- fused node GEMMs via split-precision bf16 MFMA; xl output as fp16 ----
template <int DIN, bool RELU>
__global__ __launch_bounds__(256, 3) void k_gemm(
        const float* __restrict__ xin, const short* __restrict__ Ws,
        const float* __restrict__ bvec, const float* __restrict__ rb,
        _Float16* __restrict__ xl16, float* __restrict__ xr, float* __restrict__ acc) {
    constexpr int LROW = 40;
    __shared__ short lds[20480];            // 40 KB
    short* xhi = lds;
    short* xlo = lds + 2560;

    const int tid = threadIdx.x;
    const int w = tid >> 6;
    const int lane = tid & 63;
    const int col = lane & 15;
    const int quad = lane >> 4;
    const int nb0 = blockIdx.x * 64;

    f32x4 d[3][4];
#pragma unroll
    for (int m = 0; m < 3; m++)
#pragma unroll
        for (int ct = 0; ct < 4; ct++) d[m][ct] = (f32x4){0.f, 0.f, 0.f, 0.f};

    for (int c0 = 0; c0 < DIN; c0 += 32) {
        if (c0) __syncthreads();
        for (int u = tid; u < 512; u += 256) {
            int row = u >> 3, kq = u & 7;
            int n = nb0 + row;
            float4 v = make_float4(0.f, 0.f, 0.f, 0.f);
            if (n < NN) {
                v = *(const float4*)&xin[(size_t)n * DIN + c0 + 4 * kq];
                if (RELU) {
                    v.x = fmaxf(v.x, 0.f); v.y = fmaxf(v.y, 0.f);
                    v.z = fmaxf(v.z, 0.f); v.w = fmaxf(v.w, 0.f);
                }
            }
            s4v h, l;
            short h0 = split_hi(v.x), l0 = split_lo(v.x, h0);
            short h1 = split_hi(v.y), l1 = split_lo(v.y, h1);
            short h2 = split_hi(v.z), l2 = split_lo(v.z, h2);
            short h3 = split_hi(v.w), l3 = split_lo(v.w, h3);
            h[0] = h0; h[1] = h1; h[2] = h2; h[3] = h3;
            l[0] = l0; l[1] = l1; l[2] = l2; l[3] = l3;
            *(s4v*)&xhi[row * LROW + 4 * kq] = h;
            *(s4v*)&xlo[row * LROW + 4 * kq] = l;
        }
        for (int u = tid; u < 1536; u += 256) {
            int mp = u >> 8;
            int r = u & 255;
            int c = r >> 2, q = r & 3;
            s8v v = *(const s8v*)&Ws[((mp * HID + c) * DIN) + c0 + 8 * q];
            *(s8v*)&lds[5120 + mp * 2560 + c * LROW + 8 * q] = v;
        }
        __syncthreads();

        bf16x8 a_h = __builtin_bit_cast(bf16x8,
            *(const s8v*)&xhi[(w * 16 + col) * LROW + quad * 8]);
        bf16x8 a_l = __builtin_bit_cast(bf16x8,
            *(const s8v*)&xlo[(w * 16 + col) * LROW + quad * 8]);

#pragma unroll
        for (int m = 0; m < 3; m++) {
#pragma unroll
            for (int ct = 0; ct < 4; ct++) {
                bf16x8 b_h = __builtin_bit_cast(bf16x8,
                    *(const s8v*)&lds[5120 + (m * 2 + 0) * 2560 + (ct * 16 + col) * LROW + quad * 8]);
                bf16x8 b_l = __builtin_bit_cast(bf16x8,
                    *(const s8v*)&lds[5120 + (m * 2 + 1) * 2560 + (ct * 16 + col) * LROW + quad * 8]);
                d[m][ct] = __builtin_amdgcn_mfma_f32_16x16x32_bf16(a_h, b_h, d[m][ct], 0, 0, 0);
                d[m][ct] = __builtin_amdgcn_mfma_f32_16x16x32_bf16(a_h, b_l, d[m][ct], 0, 0, 0);
                d[m][ct] = __builtin_amdgcn_mfma_f32_16x16x32_bf16(a_l, b_h, d[m][ct], 0, 0, 0);
            }
        }
    }

#pragma unroll
    for (int r = 0; r < 4; r++) {
        int n = nb0 + w * 16 + quad * 4 + r;
        if (n >= NN) continue;
        size_t base = (size_t)n * HID;
#pragma unroll
        for (int ct = 0; ct < 4; ct++) {
            int c = ct * 16 + col;
            xl16[base + c] = (_Float16)d[0][ct][r];
            xr[base + c] = d[1][ct][r];
            acc[base + c] = d[2][ct][r] + bvec[c] + rb[c];
        }
    }
}

// ---- fused per-dst attention: 16 edges/iter (2 per e-slot) x 8 channels ----
__global__ __launch_bounds__(256) void k_attn_dst(
        const int* __restrict__ off, const u16* __restrict__ srcs,
        const _Float16* __restrict__ xl16, const float* __restrict__ xr,
        const float* __restrict__ att, float* __restrict__ acc) {
    const int lane = threadIdx.x & 63;
    const int d = blockIdx.x * 4 + (threadIdx.x >> 6);
    if (d >= NN) return;
    const int e = lane >> 3;
    const int cg = lane & 7;

    const float4* xr4 = (const float4*)&xr[(size_t)d * HID + 8 * cg];
    float4 xra = xr4[0], xrb = xr4[1];
    const float4* at4 = (const float4*)&att[8 * cg];
    float4 ata = at4[0], atb = at4[1];

#define EDGE_LOGIT(S, XA, XB, T)                                               \
    {                                                                          \
        h8v _hv = *(const h8v*)&xl16[(size_t)(S) * HID + 8 * cg];              \
        XA.x = (float)_hv[0]; XA.y = (float)_hv[1];                            \
        XA.z = (float)_hv[2]; XA.w = (float)_hv[3];                            \
        XB.x = (float)_hv[4]; XB.y = (float)_hv[5];                            \
        XB.z = (float)_hv[6]; XB.w = (float)_hv[7];                            \
        float _ps;                                                             \
        float _v;                                                              \
        _v = XA.x + xra.x; _ps  = (fmaxf(_v,0.f) + NEG*fminf(_v,0.f)) * ata.x; \
        _v = XA.y + xra.y; _ps += (fmaxf(_v,0.f) + NEG*fminf(_v,0.f)) * ata.y; \
        _v = XA.z + xra.z; _ps += (fmaxf(_v,0.f) + NEG*fminf(_v,0.f)) * ata.z; \
        _v = XA.w + xra.w; _ps += (fmaxf(_v,0.f) + NEG*fminf(_v,0.f)) * ata.w; \
        _v = XB.x + xrb.x; _ps += (fmaxf(_v,0.f) + NEG*fminf(_v,0.f)) * atb.x; \
        _v = XB.y + xrb.y; _ps += (fmaxf(_v,0.f) + NEG*fminf(_v,0.f)) * atb.y; \
        _v = XB.z + xrb.z; _ps += (fmaxf(_v,0.f) + NEG*fminf(_v,0.f)) * atb.z; \
        _v = XB.w + xrb.w; _ps += (fmaxf(_v,0.f) + NEG*fminf(_v,0.f)) * atb.w; \
        _ps += __shfl_xor(_ps, 1, 64);                                         \
        _ps += __shfl_xor(_ps, 2, 64);                                         \
        _ps += __shfl_xor(_ps, 4, 64);                                         \
        T = _ps;                                                               \
    }

    float m, l;
    float4 oA, oB;
    {
        float4 xla, xlb; float t;
        EDGE_LOGIT(d, xla, xlb, t);
        m = t;
        bool own = (e == 0);
        l = own ? 1.f : 0.f;
        oA = own ? xla : make_float4(0.f, 0.f, 0.f, 0.f);
        oB = own ? xlb : make_float4(0.f, 0.f, 0.f, 0.f);
    }

    const int lo = off[d], deg = off[d + 1] - lo;
    for (int base = 0; base < deg; base += 16) {
        int sv = 0;
        if (lane < 16) sv = (int)srcs[lo + min(base + lane, deg - 1)];
        int s0 = __shfl(sv, e, 64);
        int s1 = __shfl(sv, e + 8, 64);

        float4 xa0, xb0, xa1, xb1; float t0, t1;
        EDGE_LOGIT(s0, xa0, xb0, t0);
        EDGE_LOGIT(s1, xa1, xb1, t1);
        if (base + e >= deg) t0 = -INFINITY;
        if (base + 8 + e >= deg) t1 = -INFINITY;

        float cm = fmaxf(t0, t1);
        cm = fmaxf(cm, __shfl_xor(cm, 8, 64));
        cm = fmaxf(cm, __shfl_xor(cm, 16, 64));
        cm = fmaxf(cm, __shfl_xor(cm, 32, 64));
        float newm = fmaxf(m, cm);
        float corr = __expf(m - newm);
        float p0 = __expf(t0 - newm);
        float p1 = __expf(t1 - newm);
        m = newm;
        l = l * corr + p0 + p1;
        oA.x = oA.x * corr + p0 * xa0.x + p1 * xa1.x;
        oA.y = oA.y * corr + p0 * xa0.y + p1 * xa1.y;
        oA.z = oA.z * corr + p0 * xa0.z + p1 * xa1.z;
        oA.w = oA.w * corr + p0 * xa0.w + p1 * xa1.w;
        oB.x = oB.x * corr + p0 * xb0.x + p1 * xb1.x;
        oB.y = oB.y * corr + p0 * xb0.y + p1 * xb1.y;
        oB.z = oB.z * corr + p0 * xb0.z + p1 * xb1.z;
        oB.w = oB.w * corr + p0 * xb0.w + p1 * xb1.w;
    }
#undef EDGE_LOGIT

#pragma unroll
    for (int w = 8; w <= 32; w <<= 1) {
        l    += __shfl_xor(l, w, 64);
        oA.x += __shfl_xor(oA.x, w, 64); oA.y += __shfl_xor(oA.y, w, 64);
        oA.z += __shfl_xor(oA.z, w, 64); oA.w += __shfl_xor(oA.w, w, 64);
        oB.x += __shfl_xor(oB.x, w, 64); oB.y += __shfl_xor(oB.y, w, 64);
        oB.z += __shfl_xor(oB.z, w, 64); oB.w += __shfl_xor(oB.w, w, 64);
    }

    if (e == 0) {
        float inv = 1.f / l;
        float4* a4 = (float4*)&acc[(size_t)d * HID + 8 * cg];
        float4 c0 = a4[0], c1 = a4[1];
        c0.x += oA.x * inv; c0.y += oA.y * inv;
        c0.z += oA.z * inv; c0.w += oA.w * inv;
        c1.x += oB.x * inv; c1.y += oB.y * inv;
        c1.z += oB.z * inv; c1.w += oB.w * inv;
        a4[0] = c0; a4[1] = c1;
    }
}

// ---- fused mean-pool + head ----
__global__ __launch_bounds__(512) void k_pool_final(
        const float* __restrict__ acc,
        const int* __restrict__ startg, const int* __restrict__ endg,
        const float* __restrict__ Wf, const float* __restrict__ bf_,
        float* __restrict__ out) {
    __shared__ float red[8][HID];
    const int g = blockIdx.x;
    const int c = threadIdx.x & 63;
    const int j = threadIdx.x >> 6;
    const int s = startg[g], epos = endg[g];

    float sum = 0.f;
    for (int n = s + j; n < epos; n += 8)
        sum += acc[(size_t)n * HID + c];
    red[j][c] = sum;
    __syncthreads();

    if (threadIdx.x < HID) {
        float tot = 0.f;
#pragma unroll
        for (int w = 0; w < 8; w++) tot += red[w][c];
        float cntf = (float)(epos - s);
        float v = tot / fmaxf(cntf, 1.f) * Wf[c];
#pragma unroll
        for (int o = 32; o; o >>= 1) v += __shfl_xor(v, o, 64);
        if (c == 0) out[g] = v + bf_[0];
    }
}

extern "C" void kernel_launch(void* const* d_in, const int* in_sizes, int n_in,
                              void* d_out, int out_size, void* d_ws, size_t ws_size,
                              hipStream_t stream) {
    const float* x   = (const float*)d_in[0];
    const int* eidx  = (const int*)d_in[1];
    const int* batch = (const int*)d_in[2];
    const int* esrc = eidx;
    const int* edst = eidx + NE;
    const float* Wf  = (const float*)d_in[21];
    const float* bfb = (const float*)d_in[22];

    float* wsf = (float*)d_ws;
    const size_t NN64 = (size_t)NN * HID;
    _Float16* xl16 = (_Float16*)wsf;                // NN64 halfs
    float* xr     = wsf + NN64;
    float* acc0   = xr + NN64;
    float* acc1   = acc0 + NN64;
    short* Ws0    = (short*)(acc1 + NN64);
    short* Ws1    = Ws0 + 2 * 3 * HID * DIN0;
    short* Ws2    = Ws1 + 2 * 3 * HID * HID;
    int*   ccnt   = (int*)(Ws2 + 2 * 3 * HID * HID);
    int*   startg = ccnt + NN;
    int*   endg   = startg + NG;
    int*   off    = endg + NG;
    int*   cursor = off + NN + 1;
    int*   part   = cursor + NN;
    int*   partSc = part + SNB;
    int*   cnt8   = partSc + SNB;
    u16*   srcs   = (u16*)(cnt8 + 8 * NN);          // NE u16

    k_wt_all<<<(3 * HID * DIN0 + 2 * 3 * HID * HID + 255) / 256, 256, 0, stream>>>(
        (const float*)d_in[3], (const float*)d_in[4], (const float*)d_in[7],
        (const float*)d_in[9], (const float*)d_in[10], (const float*)d_in[13],
        (const float*)d_in[15], (const float*)d_in[16], (const float*)d_in[19],
        Ws0, Ws1, Ws2, startg, endg);
    k_bounds<<<(NN + 255) / 256, 256, 0, stream>>>(batch, startg, endg, cnt8);

    k_hist8<<<512, 256, 0, stream>>>(edst, cnt8);
    k_hist_red<<<(NN + 255) / 256, 256, 0, stream>>>(cnt8, ccnt);
    k_scan_part<<<SNB, 256, 0, stream>>>(ccnt, part);
    k_scan_small<<<1, 64, 0, stream>>>(part, partSc);
    k_scan_emit<<<SNB, 256, 0, stream>>>(ccnt, partSc, off, cursor);
    k_scatter_ids<<<8 * SCAT_BPG, 256, 0, stream>>>(esrc, edst, cursor, srcs);

    const short* Wss[3] = {Ws0, Ws1, Ws2};
    float* accs[4] = {acc0, acc0, acc1, acc0};  // out of layer L = accs[L+1]
    const int gemm_grid = (NN + 63) / 64;
    for (int L = 0; L < 3; L++) {
        const float* att = (const float*)d_in[3 + L * 6 + 2];
        const float* b   = (const float*)d_in[3 + L * 6 + 3];
        const float* Rb  = (const float*)d_in[3 + L * 6 + 5];
        float* accOut = accs[L + 1];

        if (L == 0)
            k_gemm<DIN0, false><<<gemm_grid, 256, 0, stream>>>(
                x, Wss[0], b, Rb, xl16, xr, accOut);
        else
            k_gemm<HID, true><<<gemm_grid, 256, 0, stream>>>(
                accs[L], Wss[L], b, Rb, xl16, xr, accOut);

        k_attn_dst<<<(NN + 3) / 4, 256, 0, stream>>>(off, srcs, xl16, xr, att, accOut);
    }

    k_pool_final<<<NG, 512, 0, stream>>>(accs[3], startg, endg, Wf, bfb, (float*)d_out);
}

// Round 20
// 369.785 us; speedup vs baseline: 1.4354x; 1.1040x over previous
//
#include <hip/hip_runtime.h>

// GATv2 3-layer + mean-pool + linear head, MI355X.
// R19: atomic-free CSR scatter. k_hist8's atomicAdd return value IS a
// per-(slice,dst) rank -> store it (coalesced u16); k_hist_red converts cnt8
// to per-dst slice-exclusive prefixes; k_scatter_rank places each edge at
// off[d]+sliceBase+rank with plain stores, one pass (was: 8x edge re-stream
// + 1M cursor atomics = 67MB of traffic at 1.3TB/s = 53us).

#define NN 50000
#define NE 1000000
#define HID 64
#define DIN0 128
#define NG 256
#define NEG 0.2f

#define SCHUNK 1024
#define SNB ((NN + SCHUNK - 1) / SCHUNK)   // 49 blocks

typedef float f32x4 __attribute__((ext_vector_type(4)));
typedef short s8v __attribute__((ext_vector_type(8)));
typedef short s4v __attribute__((ext_vector_type(4)));
typedef __bf16 bf16x8 __attribute__((ext_vector_type(8)));
typedef _Float16 h8v __attribute__((ext_vector_type(8)));
typedef unsigned short u16;

__device__ __forceinline__ unsigned short f2bf(float f) {
    unsigned u = __float_as_uint(f);
    u = u + 0x7fffu + ((u >> 16) & 1u);   // RNE
    return (unsigned short)(u >> 16);
}
__device__ __forceinline__ float bf2f(unsigned short v) {
    return __uint_as_float(((unsigned)v) << 16);
}
__device__ __forceinline__ short split_hi(float x) {
    return (short)f2bf(x);
}
__device__ __forceinline__ short split_lo(float x, short hi) {
    return (short)f2bf(x - bf2f((unsigned short)hi));
}

// ---- merged weight pre-split (all 3 layers) + zero startg/endg ----
__global__ __launch_bounds__(256) void k_wt_all(
        const float* __restrict__ Wl0, const float* __restrict__ Wr0, const float* __restrict__ Rw0,
        const float* __restrict__ Wl1, const float* __restrict__ Wr1, const float* __restrict__ Rw1,
        const float* __restrict__ Wl2, const float* __restrict__ Wr2, const float* __restrict__ Rw2,
        short* __restrict__ Ws0, short* __restrict__ Ws1, short* __restrict__ Ws2,
        int* __restrict__ startg, int* __restrict__ endg) {
    int i = blockIdx.x * 256 + threadIdx.x;
    if (i < 2 * NG) {
        if (i < NG) startg[i] = 0; else endg[i - NG] = 0;
    }
    const int L0N = 3 * HID * DIN0;
    const int L1N = 3 * HID * HID;
    if (i >= L0N + 2 * L1N) return;
    const float* Wm; short* Ws; int din, local;
    if (i < L0N) {
        local = i; din = DIN0; Ws = Ws0;
        int m = local / (DIN0 * HID);
        Wm = (m == 0) ? Wl0 : (m == 1) ? Wr0 : Rw0;
    } else if (i < L0N + L1N) {
        local = i - L0N; din = HID; Ws = Ws1;
        int m = local / (HID * HID);
        Wm = (m == 0) ? Wl1 : (m == 1) ? Wr1 : Rw1;
    } else {
        local = i - L0N - L1N; din = HID; Ws = Ws2;
        int m = local / (HID * HID);
        Wm = (m == 0) ? Wl2 : (m == 1) ? Wr2 : Rw2;
    }
    int m = local / (din * HID);
    int r = local - m * (din * HID);
    int c = r / din, k = r - c * din;
    float w = Wm[c * din + k];
    short hi = split_hi(w);
    short lo = split_lo(w, hi);
    Ws[(((m * 2 + 0) * HID + c) * din) + k] = hi;
    Ws[(((m * 2 + 1) * HID + c) * din) + k] = lo;
}

// ---- graph bounds + zero hist slices ----
__global__ void k_bounds(const int* __restrict__ batch,
                         int* __restrict__ startg, int* __restrict__ endg,
                         int* __restrict__ cnt8) {
    int i = blockIdx.x * 256 + threadIdx.x;
    if (i >= NN) return;
#pragma unroll
    for (int g = 0; g < 8; g++) cnt8[g * NN + i] = 0;
    int g = batch[i];
    if (i == 0 || batch[i - 1] != g) startg[g] = i;
    if (i == NN - 1 || batch[i + 1] != g) endg[g] = i + 1;
}

// ---- XCD-sliced histogram; atomic return = rank within (slice,dst) ----
__global__ __launch_bounds__(256) void k_hist8(const int* __restrict__ edst,
                                               int* __restrict__ cnt8,
                                               u16* __restrict__ rank) {
    int* mycnt = cnt8 + (blockIdx.x & 7) * NN;
    for (int e = blockIdx.x * 256 + threadIdx.x; e < NE; e += 512 * 256) {
        int r = atomicAdd(&mycnt[edst[e]], 1);
        rank[e] = (u16)r;
    }
}

// ---- per-dst: slice-exclusive prefixes (in place) + total ----
__global__ void k_hist_red(int* __restrict__ cnt8, int* __restrict__ cnt) {
    int i = blockIdx.x * 256 + threadIdx.x;
    if (i >= NN) return;
    int s = 0;
#pragma unroll
    for (int g = 0; g < 8; g++) {
        int t = cnt8[g * NN + i];
        cnt8[g * NN + i] = s;
        s += t;
    }
    cnt[i] = s;
}

__global__ __launch_bounds__(256) void k_scan_part(const int* __restrict__ cnt,
                                                   int* __restrict__ part) {
    __shared__ int ws[4];
    int b = blockIdx.x, t = threadIdx.x;
    int i0 = b * SCHUNK + t * 4;
    int s = 0;
#pragma unroll
    for (int j = 0; j < 4; j++) {
        int i = i0 + j;
        if (i < NN) s += cnt[i];
    }
#pragma unroll
    for (int o = 32; o; o >>= 1) s += __shfl_xor(s, o, 64);
    if ((t & 63) == 0) ws[t >> 6] = s;
    __syncthreads();
    if (t == 0) part[b] = ws[0] + ws[1] + ws[2] + ws[3];
}

__global__ void k_scan_small(const int* __restrict__ part, int* __restrict__ partScan) {
    __shared__ int sh[SNB];
    int t = threadIdx.x;
    if (t < SNB) sh[t] = part[t];
    __syncthreads();
    if (t < SNB) {
        int s = 0;
        for (int i = 0; i < t; i++) s += sh[i];
        partScan[t] = s;
    }
}

__global__ __launch_bounds__(256) void k_scan_emit(const int* __restrict__ cnt,
                                                   const int* __restrict__ partScan,
                                                   int* __restrict__ off) {
    __shared__ int tsum[256];
    int b = blockIdx.x, t = threadIdx.x;
    int i0 = b * SCHUNK + t * 4;
    int e[4], p[4];
    int s = 0;
#pragma unroll
    for (int j = 0; j < 4; j++) {
        int i = i0 + j;
        e[j] = (i < NN) ? cnt[i] : 0;
        p[j] = s;
        s += e[j];
    }
    tsum[t] = s;
    __syncthreads();
    for (int d = 1; d < 256; d <<= 1) {
        int v = (t >= d) ? tsum[t - d] : 0;
        __syncthreads();
        tsum[t] += v;
        __syncthreads();
    }
    int base = partScan[b] + ((t == 0) ? 0 : tsum[t - 1]);
#pragma unroll
    for (int j = 0; j < 4; j++) {
        int i = i0 + j;
        if (i < NN) {
            int v = base + p[j];
            off[i] = v;
            if (i == NN - 1) off[NN] = v + e[j];
        }
    }
}

// ---- atomic-free scatter: pos = off[d] + sliceBase[slice][d] + rank[e] ----
__global__ __launch_bounds__(256) void k_scatter_rank(
        const int* __restrict__ esrc, const int* __restrict__ edst,
        const int* __restrict__ off, const int* __restrict__ cnt8,
        const u16* __restrict__ rank, u16* __restrict__ srcs) {
    int e = blockIdx.x * 256 + threadIdx.x;
    if (e >= NE) return;
    int d = edst[e];
    int slice = (e >> 8) & 7;               // matches k_hist8's block mapping
    int pos = off[d] + cnt8[slice * NN + d] + (int)rank[e];
    srcs[pos] = (u16)esrc[e];
}

// ---- fused node GEMMs via split-precision bf16 MFMA; xl output as fp16 ----
template <int DIN, bool RELU>
__global__ __launch_bounds__(256, 3) void k_gemm(
        const float* __restrict__ xin, const short* __restrict__ Ws,
        const float* __restrict__ bvec, const float* __restrict__ rb,
        _Float16* __restrict__ xl16, float* __restrict__ xr, float* __restrict__ acc) {
    constexpr int LROW = 40;
    __shared__ short lds[20480];            // 40 KB
    short* xhi = lds;
    short* xlo = lds + 2560;

    const int tid = threadIdx.x;
    const int w = tid >> 6;
    const int lane = tid & 63;
    const int col = lane & 15;
    const int quad = lane >> 4;
    const int nb0 = blockIdx.x * 64;

    f32x4 d[3][4];
#pragma unroll
    for (int m = 0; m < 3; m++)
#pragma unroll
        for (int ct = 0; ct < 4; ct++) d[m][ct] = (f32x4){0.f, 0.f, 0.f, 0.f};

    for (int c0 = 0; c0 < DIN; c0 += 32) {
        if (c0) __syncthreads();
        for (int u = tid; u < 512; u += 256) {
            int row = u >> 3, kq = u & 7;
            int n = nb0 + row;
            float4 v = make_float4(0.f, 0.f, 0.f, 0.f);
            if (n < NN) {
                v = *(const float4*)&xin[(size_t)n * DIN + c0 + 4 * kq];
                if (RELU) {
                    v.x = fmaxf(v.x, 0.f); v.y = fmaxf(v.y, 0.f);
                    v.z = fmaxf(v.z, 0.f); v.w = fmaxf(v.w, 0.f);
                }
            }
            s4v h, l;
            short h0 = split_hi(v.x), l0 = split_lo(v.x, h0);
            short h1 = split_hi(v.y), l1 = split_lo(v.y, h1);
            short h2 = split_hi(v.z), l2 = split_lo(v.z, h2);
            short h3 = split_hi(v.w), l3 = split_lo(v.w, h3);
            h[0] = h0; h[1] = h1; h[2] = h2; h[3] = h3;
            l[0] = l0; l[1] = l1; l[2] = l2; l[3] = l3;
            *(s4v*)&xhi[row * LROW + 4 * kq] = h;
            *(s4v*)&xlo[row * LROW + 4 * kq] = l;
        }
        for (int u = tid; u < 1536; u += 256) {
            int mp = u >> 8;
            int r = u & 255;
            int c = r >> 2, q = r & 3;
            s8v v = *(const s8v*)&Ws[((mp * HID + c) * DIN) + c0 + 8 * q];
            *(s8v*)&lds[5120 + mp * 2560 + c * LROW + 8 * q] = v;
        }
        __syncthreads();

        bf16x8 a_h = __builtin_bit_cast(bf16x8,
            *(const s8v*)&xhi[(w * 16 + col) * LROW + quad * 8]);
        bf16x8 a_l = __builtin_bit_cast(bf16x8,
            *(const s8v*)&xlo[(w * 16 + col) * LROW + quad * 8]);

#pragma unroll
        for (int m = 0; m < 3; m++) {
#pragma unroll
            for (int ct = 0; ct < 4; ct++) {
                bf16x8 b_h = __builtin_bit_cast(bf16x8,
                    *(const s8v*)&lds[5120 + (m * 2 + 0) * 2560 + (ct * 16 + col) * LROW + quad * 8]);
                bf16x8 b_l = __builtin_bit_cast(bf16x8,
                    *(const s8v*)&lds[5120 + (m * 2 + 1) * 2560 + (ct * 16 + col) * LROW + quad * 8]);
                d[m][ct] = __builtin_amdgcn_mfma_f32_16x16x32_bf16(a_h, b_h, d[m][ct], 0, 0, 0);
                d[m][ct] = __builtin_amdgcn_mfma_f32_16x16x32_bf16(a_h, b_l, d[m][ct], 0, 0, 0);
                d[m][ct] = __builtin_amdgcn_mfma_f32_16x16x32_bf16(a_l, b_h, d[m][ct], 0, 0, 0);
            }
        }
    }

#pragma unroll
    for (int r = 0; r < 4; r++) {
        int n = nb0 + w * 16 + quad * 4 + r;
        if (n >= NN) continue;
        size_t base = (size_t)n * HID;
#pragma unroll
        for (int ct = 0; ct < 4; ct++) {
            int c = ct * 16 + col;
            xl16[base + c] = (_Float16)d[0][ct][r];
            xr[base + c] = d[1][ct][r];
            acc[base + c] = d[2][ct][r] + bvec[c] + rb[c];
        }
    }
}

// ---- fused per-dst attention: 16 edges/iter (2 per e-slot) x 8 channels ----
__global__ __launch_bounds__(256) void k_attn_dst(
        const int* __restrict__ off, const u16* __restrict__ srcs,
        const _Float16* __restrict__ xl16, const float* __restrict__ xr,
        const float* __restrict__ att, float* __restrict__ acc) {
    const int lane = threadIdx.x & 63;
    const int d = blockIdx.x * 4 + (threadIdx.x >> 6);
    if (d >= NN) return;
    const int e = lane >> 3;
    const int cg = lane & 7;

    const float4* xr4 = (const float4*)&xr[(size_t)d * HID + 8 * cg];
    float4 xra = xr4[0], xrb = xr4[1];
    const float4* at4 = (const float4*)&att[8 * cg];
    float4 ata = at4[0], atb = at4[1];

#define EDGE_LOGIT(S, XA, XB, T)                                               \
    {                                                                          \
        h8v _hv = *(const h8v*)&xl16[(size_t)(S) * HID + 8 * cg];              \
        XA.x = (float)_hv[0]; XA.y = (float)_hv[1];                            \
        XA.z = (float)_hv[2]; XA.w = (float)_hv[3];                            \
        XB.x = (float)_hv[4]; XB.y = (float)_hv[5];                            \
        XB.z = (float)_hv[6]; XB.w = (float)_hv[7];                            \
        float _ps;                                                             \
        float _v;                                                              \
        _v = XA.x + xra.x; _ps  = (fmaxf(_v,0.f) + NEG*fminf(_v,0.f)) * ata.x; \
        _v = XA.y + xra.y; _ps += (fmaxf(_v,0.f) + NEG*fminf(_v,0.f)) * ata.y; \
        _v = XA.z + xra.z; _ps += (fmaxf(_v,0.f) + NEG*fminf(_v,0.f)) * ata.z; \
        _v = XA.w + xra.w; _ps += (fmaxf(_v,0.f) + NEG*fminf(_v,0.f)) * ata.w; \
        _v = XB.x + xrb.x; _ps += (fmaxf(_v,0.f) + NEG*fminf(_v,0.f)) * atb.x; \
        _v = XB.y + xrb.y; _ps += (fmaxf(_v,0.f) + NEG*fminf(_v,0.f)) * atb.y; \
        _v = XB.z + xrb.z; _ps += (fmaxf(_v,0.f) + NEG*fminf(_v,0.f)) * atb.z; \
        _v = XB.w + xrb.w; _ps += (fmaxf(_v,0.f) + NEG*fminf(_v,0.f)) * atb.w; \
        _ps += __shfl_xor(_ps, 1, 64);                                         \
        _ps += __shfl_xor(_ps, 2, 64);                                         \
        _ps += __shfl_xor(_ps, 4, 64);                                         \
        T = _ps;                                                               \
    }

    float m, l;
    float4 oA, oB;
    {
        float4 xla, xlb; float t;
        EDGE_LOGIT(d, xla, xlb, t);
        m = t;
        bool own = (e == 0);
        l = own ? 1.f : 0.f;
        oA = own ? xla : make_float4(0.f, 0.f, 0.f, 0.f);
        oB = own ? xlb : make_float4(0.f, 0.f, 0.f, 0.f);
    }

    const int lo = off[d], deg = off[d + 1] - lo;
    for (int base = 0; base < deg; base += 16) {
        int sv = 0;
        if (lane < 16) sv = (int)srcs[lo + min(base + lane, deg - 1)];
        int s0 = __shfl(sv, e, 64);
        int s1 = __shfl(sv, e + 8, 64);

        float4 xa0, xb0, xa1, xb1; float t0, t1;
        EDGE_LOGIT(s0, xa0, xb0, t0);
        EDGE_LOGIT(s1, xa1, xb1, t1);
        if (base + e >= deg) t0 = -INFINITY;
        if (base + 8 + e >= deg) t1 = -INFINITY;

        float cm = fmaxf(t0, t1);
        cm = fmaxf(cm, __shfl_xor(cm, 8, 64));
        cm = fmaxf(cm, __shfl_xor(cm, 16, 64));
        cm = fmaxf(cm, __shfl_xor(cm, 32, 64));
        float newm = fmaxf(m, cm);
        float corr = __expf(m - newm);
        float p0 = __expf(t0 - newm);
        float p1 = __expf(t1 - newm);
        m = newm;
        l = l * corr + p0 + p1;
        oA.x = oA.x * corr + p0 * xa0.x + p1 * xa1.x;
        oA.y = oA.y * corr + p0 * xa0.y + p1 * xa1.y;
        oA.z = oA.z * corr + p0 * xa0.z + p1 * xa1.z;
        oA.w = oA.w * corr + p0 * xa0.w + p1 * xa1.w;
        oB.x = oB.x * corr + p0 * xb0.x + p1 * xb1.x;
        oB.y = oB.y * corr + p0 * xb0.y + p1 * xb1.y;
        oB.z = oB.z * corr + p0 * xb0.z + p1 * xb1.z;
        oB.w = oB.w * corr + p0 * xb0.w + p1 * xb1.w;
    }
#undef EDGE_LOGIT

#pragma unroll
    for (int w = 8; w <= 32; w <<= 1) {
        l    += __shfl_xor(l, w, 64);
        oA.x += __shfl_xor(oA.x, w, 64); oA.y += __shfl_xor(oA.y, w, 64);
        oA.z += __shfl_xor(oA.z, w, 64); oA.w += __shfl_xor(oA.w, w, 64);
        oB.x += __shfl_xor(oB.x, w, 64); oB.y += __shfl_xor(oB.y, w, 64);
        oB.z += __shfl_xor(oB.z, w, 64); oB.w += __shfl_xor(oB.w, w, 64);
    }

    if (e == 0) {
        float inv = 1.f / l;
        float4* a4 = (float4*)&acc[(size_t)d * HID + 8 * cg];
        float4 c0 = a4[0], c1 = a4[1];
        c0.x += oA.x * inv; c0.y += oA.y * inv;
        c0.z += oA.z * inv; c0.w += oA.w * inv;
        c1.x += oB.x * inv; c1.y += oB.y * inv;
        c1.z += oB.z * inv; c1.w += oB.w * inv;
        a4[0] = c0; a4[1] = c1;
    }
}

// ---- fused mean-pool + head ----
__global__ __launch_bounds__(512) void k_pool_final(
        const float* __restrict__ acc,
        const int* __restrict__ startg, const int* __restrict__ endg,
        const float* __restrict__ Wf, const float* __restrict__ bf_,
        float* __restrict__ out) {
    __shared__ float red[8][HID];
    const int g = blockIdx.x;
    const int c = threadIdx.x & 63;
    const int j = threadIdx.x >> 6;
    const int s = startg[g], epos = endg[g];

    float sum = 0.f;
    for (int n = s + j; n < epos; n += 8)
        sum += acc[(size_t)n * HID + c];
    red[j][c] = sum;
    __syncthreads();

    if (threadIdx.x < HID) {
        float tot = 0.f;
#pragma unroll
        for (int w = 0; w < 8; w++) tot += red[w][c];
        float cntf = (float)(epos - s);
        float v = tot / fmaxf(cntf, 1.f) * Wf[c];
#pragma unroll
        for (int o = 32; o; o >>= 1) v += __shfl_xor(v, o, 64);
        if (c == 0) out[g] = v + bf_[0];
    }
}

extern "C" void kernel_launch(void* const* d_in, const int* in_sizes, int n_in,
                              void* d_out, int out_size, void* d_ws, size_t ws_size,
                              hipStream_t stream) {
    const float* x   = (const float*)d_in[0];
    const int* eidx  = (const int*)d_in[1];
    const int* batch = (const int*)d_in[2];
    const int* esrc = eidx;
    const int* edst = eidx + NE;
    const float* Wf  = (const float*)d_in[21];
    const float* bfb = (const float*)d_in[22];

    float* wsf = (float*)d_ws;
    const size_t NN64 = (size_t)NN * HID;
    _Float16* xl16 = (_Float16*)wsf;                // NN64 halfs
    float* xr     = wsf + NN64;
    float* acc0   = xr + NN64;
    float* acc1   = acc0 + NN64;
    short* Ws0    = (short*)(acc1 + NN64);
    short* Ws1    = Ws0 + 2 * 3 * HID * DIN0;
    short* Ws2    = Ws1 + 2 * 3 * HID * HID;
    int*   ccnt   = (int*)(Ws2 + 2 * 3 * HID * HID);
    int*   startg = ccnt + NN;
    int*   endg   = startg + NG;
    int*   off    = endg + NG;
    int*   part   = off + NN + 1;
    int*   partSc = part + SNB;
    int*   cnt8   = partSc + SNB;                   // 8*NN
    u16*   rank   = (u16*)(cnt8 + 8 * NN);          // NE u16
    u16*   srcs   = rank + NE;                      // NE u16

    k_wt_all<<<(3 * HID * DIN0 + 2 * 3 * HID * HID + 255) / 256, 256, 0, stream>>>(
        (const float*)d_in[3], (const float*)d_in[4], (const float*)d_in[7],
        (const float*)d_in[9], (const float*)d_in[10], (const float*)d_in[13],
        (const float*)d_in[15], (const float*)d_in[16], (const float*)d_in[19],
        Ws0, Ws1, Ws2, startg, endg);
    k_bounds<<<(NN + 255) / 256, 256, 0, stream>>>(batch, startg, endg, cnt8);

    k_hist8<<<512, 256, 0, stream>>>(edst, cnt8, rank);
    k_hist_red<<<(NN + 255) / 256, 256, 0, stream>>>(cnt8, ccnt);
    k_scan_part<<<SNB, 256, 0, stream>>>(ccnt, part);
    k_scan_small<<<1, 64, 0, stream>>>(part, partSc);
    k_scan_emit<<<SNB, 256, 0, stream>>>(ccnt, partSc, off);
    k_scatter_rank<<<(NE + 255) / 256, 256, 0, stream>>>(esrc, edst, off, cnt8, rank, srcs);

    const short* Wss[3] = {Ws0, Ws1, Ws2};
    float* accs[4] = {acc0, acc0, acc1, acc0};  // out of layer L = accs[L+1]
    const int gemm_grid = (NN + 63) / 64;
    for (int L = 0; L < 3; L++) {
        const float* att = (const float*)d_in[3 + L * 6 + 2];
        const float* b   = (const float*)d_in[3 + L * 6 + 3];
        const float* Rb  = (const float*)d_in[3 + L * 6 + 5];
        float* accOut = accs[L + 1];

        if (L == 0)
            k_gemm<DIN0, false><<<gemm_grid, 256, 0, stream>>>(
                x, Wss[0], b, Rb, xl16, xr, accOut);
        else
            k_gemm<HID, true><<<gemm_grid, 256, 0, stream>>>(
                accs[L], Wss[L], b, Rb, xl16, xr, accOut);

        k_attn_dst<<<(NN + 3) / 4, 256, 0, stream>>>(off, srcs, xl16, xr, att, accOut);
    }

    k_pool_final<<<NG, 512, 0, stream>>>(accs[3], startg, endg, Wf, bfb, (float*)d_out);
}